// Round 1
// baseline (2319.266 us; speedup 1.0000x reference)
//
#include <hip/hip_runtime.h>
#include <hip/hip_bf16.h>

#define DI __device__ __forceinline__

constexpr int  NP        = 65536;              // H*W per batch
constexpr long GP_STRIDE = 20672;              // 5*4096 + 192

// workspace byte offsets
constexpr long WSO_GP    = 0;                                  // [2][128][GP_STRIDE] f32
constexpr long WSO_M     = WSO_GP    + 2L*128*GP_STRIDE*4;     // [2][5][4096] f32
constexpr long WSO_S     = WSO_M     + 2L*5*4096*4;            // [2][192] f32
constexpr long WSO_P     = WSO_S     + 2L*192*4;               // [2][5][4096] f32
constexpr long WSO_QK    = WSO_P     + 2L*5*4096*4;            // [2][2][4096] f32
constexpr long WSO_G     = WSO_QK    + 2L*2*4096*4;            // [2][2][4096] f32
constexpr long WSO_WKT   = WSO_G     + 2L*2*4096*4;            // [4096] f32
constexpr long WSO_WCAT  = WSO_WKT   + 4096L*4;                // [192][9][128] f32
constexpr long WSO_W2T   = WSO_WCAT  + 221184L*4;              // [64][9][64] f32
constexpr long WSO_FUSED = WSO_W2T   + 36864L*4;               // [2][192][NP] bf16
constexpr long WSO_Y     = WSO_FUSED + 2L*192*NP*2;            // [2][128][NP] bf16
constexpr long WSO_STATA = WSO_Y     + 2L*128*NP*2;            // [4096][256] f32
constexpr long WSO_P2A   = WSO_STATA + 4096L*256*4;            // [128][256] f32
constexpr long WSO_BNA   = WSO_P2A   + 128L*256*4;             // [256] f32
constexpr long WSO_Y2    = WSO_BNA   + 256L*4;                 // [2][64][NP] bf16
constexpr long WSO_STATB = WSO_Y2    + 2L*64*NP*2;             // [4096][128] f32
constexpr long WSO_P2B   = WSO_STATB + 4096L*128*4;            // [128][128] f32
constexpr long WSO_BNB   = WSO_P2B   + 128L*128*4;             // [128] f32
constexpr long WS_NEED   = WSO_BNB   + 128L*4;

DI float b2f(unsigned short u) { return __uint_as_float(((unsigned)u) << 16); }

// ---------------- K0: weight re-layouts ----------------
__global__ __launch_bounds__(256) void k0_prep(const float* __restrict__ w_init,
                                               const float* __restrict__ w1,
                                               const float* __restrict__ w2,
                                               const float* __restrict__ wk,
                                               float* __restrict__ wcat,
                                               float* __restrict__ w2t,
                                               float* __restrict__ wkT) {
  int i = blockIdx.x * 256 + threadIdx.x;
  if (i < 221184) {                       // wcat[c][t][o], o<64: w_init, else w1
    int c = i / 1152, r = i % 1152, t = r / 128, o = r % 128;
    float v = (o < 64) ? w_init[(o * 192 + c) * 9 + t] : w1[((o - 64) * 192 + c) * 9 + t];
    wcat[i] = v;
  } else if (i < 258048) {                // w2t[c][t][o]
    int j = i - 221184;
    int c = j / 576, r = j % 576, t = r / 64, o = r % 64;
    w2t[j] = w2[(o * 64 + c) * 9 + t];
  } else {                                // wkT[k][j] = wk[j][k]
    int j = i - 258048;
    int kk = j >> 6, oo = j & 63;
    wkT[j] = wk[oo * 64 + kk];
  }
}

// ---------------- K1: per-b Gram matrices ----------------
#define OUTER4(ACC, A, Bv)                                                     \
  ACC[0]  = fmaf(A.x, Bv.x, ACC[0]);  ACC[1]  = fmaf(A.x, Bv.y, ACC[1]);       \
  ACC[2]  = fmaf(A.x, Bv.z, ACC[2]);  ACC[3]  = fmaf(A.x, Bv.w, ACC[3]);       \
  ACC[4]  = fmaf(A.y, Bv.x, ACC[4]);  ACC[5]  = fmaf(A.y, Bv.y, ACC[5]);       \
  ACC[6]  = fmaf(A.y, Bv.z, ACC[6]);  ACC[7]  = fmaf(A.y, Bv.w, ACC[7]);       \
  ACC[8]  = fmaf(A.z, Bv.x, ACC[8]);  ACC[9]  = fmaf(A.z, Bv.y, ACC[9]);       \
  ACC[10] = fmaf(A.z, Bv.z, ACC[10]); ACC[11] = fmaf(A.z, Bv.w, ACC[11]);      \
  ACC[12] = fmaf(A.w, Bv.x, ACC[12]); ACC[13] = fmaf(A.w, Bv.y, ACC[13]);      \
  ACC[14] = fmaf(A.w, Bv.z, ACC[14]); ACC[15] = fmaf(A.w, Bv.w, ACC[15]);

__global__ __launch_bounds__(256) void k1_gram(const float* __restrict__ xi,
                                               const float* __restrict__ xe,
                                               const float* __restrict__ yy,
                                               float* __restrict__ gp) {
  __shared__ float st[3][64][68];  // transposed [tensor][n][c], padded
  int tid = threadIdx.x;
  int blk = blockIdx.x, b = blockIdx.y;
  const float* src0 = yy + (long)b * 64 * NP;
  const float* src1 = xe + (long)b * 64 * NP;
  const float* src2 = xi + (long)b * 64 * NP;
  int tc = tid & 15, td = tid >> 4;
  float acc0[16] = {0}, acc1[16] = {0}, acc2[16] = {0}, acc3[16] = {0}, acc4[16] = {0};
  float sumreg = 0.f;
  int sc_t = tid >> 6, sc_c = tid & 63;

  for (int ch = 0; ch < 8; ++ch) {
    int n0 = blk * 512 + ch * 64;
    __syncthreads();
    for (int i = tid; i < 3072; i += 256) {
      int t = i >> 10, r = i & 1023, c = r >> 4, j = r & 15;
      const float* s = (t == 0 ? src0 : (t == 1 ? src1 : src2)) + (long)c * NP + n0 + j * 4;
      float4 v = *(const float4*)s;
      st[t][j * 4 + 0][c] = v.x;
      st[t][j * 4 + 1][c] = v.y;
      st[t][j * 4 + 2][c] = v.z;
      st[t][j * 4 + 3][c] = v.w;
    }
    __syncthreads();
#pragma unroll 4
    for (int n = 0; n < 64; ++n) {
      float4 a0 = *(const float4*)&st[0][n][tc * 4];
      float4 a1 = *(const float4*)&st[1][n][tc * 4];
      float4 a2 = *(const float4*)&st[2][n][tc * 4];
      float4 b0 = *(const float4*)&st[0][n][td * 4];
      float4 b1 = *(const float4*)&st[1][n][td * 4];
      float4 b2 = *(const float4*)&st[2][n][td * 4];
      OUTER4(acc0, a0, b1)   // y . xe
      OUTER4(acc1, a0, b2)   // y . xi
      OUTER4(acc2, a0, b0)   // y . y
      OUTER4(acc3, a1, b1)   // xe . xe
      OUTER4(acc4, a2, b2)   // xi . xi
    }
    if (tid < 192) {
#pragma unroll
      for (int n = 0; n < 64; ++n) sumreg += st[sc_t][n][sc_c];
    }
  }
  float* out = gp + ((long)b * 128 + blk) * GP_STRIDE;
#define STOREG(g, ACC)                                                          \
  {                                                                             \
    _Pragma("unroll") for (int oi = 0; oi < 4; ++oi) {                          \
      float4 v = make_float4(ACC[oi * 4 + 0], ACC[oi * 4 + 1],                  \
                             ACC[oi * 4 + 2], ACC[oi * 4 + 3]);                 \
      *(float4*)&out[(g) * 4096 + (tc * 4 + oi) * 64 + td * 4] = v;             \
    }                                                                           \
  }
  STOREG(0, acc0) STOREG(1, acc1) STOREG(2, acc2) STOREG(3, acc3) STOREG(4, acc4)
  if (tid < 192) out[5 * 4096 + tid] = sumreg;
}

// ---------------- K1r: reduce Gram partials ----------------
__global__ __launch_bounds__(256) void k1_reduce(const float* __restrict__ gp,
                                                 float* __restrict__ M,
                                                 float* __restrict__ S) {
  int i = blockIdx.x * 256 + threadIdx.x;
  if (i >= 2 * GP_STRIDE) return;
  int b = i / GP_STRIDE, o = i % GP_STRIDE;
  const float* p = gp + (long)b * 128 * GP_STRIDE + o;
  float s = 0;
  for (int k = 0; k < 128; ++k) s += p[(long)k * GP_STRIDE];
  if (o < 20480) M[b * 20480 + o] = s;
  else           S[b * 192 + (o - 20480)] = s;
}

// ---------------- K2a: P_g = W * M_g ----------------
__global__ __launch_bounds__(256) void k2a(const float* __restrict__ wq,
                                           const float* __restrict__ wk,
                                           const float* __restrict__ M,
                                           float* __restrict__ P) {
  int b = blockIdx.y, g = blockIdx.x;
  const float* W = (g < 3) ? wq : wk;
  const float* Mg = M + b * 20480 + g * 4096;
  float* Pg = P + b * 20480 + g * 4096;
  int tid = threadIdx.x;
  int i = tid >> 2, jg = (tid & 3) * 16;
  float acc[16] = {0};
  for (int k = 0; k < 64; ++k) {
    float w = W[i * 64 + k];
    const float* mrow = Mg + k * 64 + jg;
#pragma unroll
    for (int j = 0; j < 16; ++j) acc[j] = fmaf(w, mrow[j], acc[j]);
  }
#pragma unroll
  for (int j = 0; j < 16; ++j) Pg[i * 64 + jg + j] = acc[j];
}

// ---------------- K2b: QK = P{0,1} * Wk^T ----------------
__global__ __launch_bounds__(256) void k2b(const float* __restrict__ P,
                                           const float* __restrict__ wkT,
                                           float* __restrict__ QK) {
  int b = blockIdx.y, v = blockIdx.x;
  const float* Pg = P + b * 20480 + v * 4096;
  float* out = QK + (b * 2 + v) * 4096;
  int tid = threadIdx.x;
  int i = tid >> 2, jg = (tid & 3) * 16;
  float acc[16] = {0};
  for (int k = 0; k < 64; ++k) {
    float w = Pg[i * 64 + k];
    const float* mrow = wkT + k * 64 + jg;
#pragma unroll
    for (int j = 0; j < 16; ++j) acc[j] = fmaf(w, mrow[j], acc[j]);
  }
#pragma unroll
  for (int j = 0; j < 16; ++j) out[i * 64 + jg + j] = acc[j];
}

// ---------------- K2c: norms, softmax, Gv = wo*BD(attn)*Wv ----------------
__global__ __launch_bounds__(256) void k2c(const float* __restrict__ P,
                                           const float* __restrict__ QK,
                                           const float* __restrict__ Ssum,
                                           const float* __restrict__ wq,
                                           const float* __restrict__ wk,
                                           const float* __restrict__ wv,
                                           const float* __restrict__ wo,
                                           const float* __restrict__ bq,
                                           const float* __restrict__ bk,
                                           const float* __restrict__ temp,
                                           float* __restrict__ G) {
  int b = blockIdx.x, tid = threadIdx.x;
  __shared__ float u[64], vxe[64], vxi[64], nq[64], nke[64], nki[64];
  __shared__ float attn[64][8];
  __shared__ float Gm[64][64];
  if (tid < 64) {
    int i = tid;
    float uu = 0, ve = 0, vi = 0, dq = 0, dke = 0, dki = 0;
    const float* p2 = P + b * 20480 + 2 * 4096 + i * 64;
    const float* p3 = P + b * 20480 + 3 * 4096 + i * 64;
    const float* p4 = P + b * 20480 + 4 * 4096 + i * 64;
    const float* sy = Ssum + b * 192;
    const float* sxe = sy + 64;
    const float* sxi = sy + 128;
#pragma unroll 8
    for (int k = 0; k < 64; ++k) {
      float wqk = wq[i * 64 + k], wkk = wk[i * 64 + k];
      uu += wqk * sy[k];  ve += wkk * sxe[k];  vi += wkk * sxi[k];
      dq += p2[k] * wqk;  dke += p3[k] * wkk;  dki += p4[k] * wkk;
    }
    u[i] = uu; vxe[i] = ve; vxi[i] = vi;
    const float N = 65536.f;
    float bqi = bq[i], bki = bk[i];
    nq[i]  = fmaxf(sqrtf(fmaxf(dq  + 2.f * uu * bqi + N * bqi * bqi, 0.f)), 1e-12f);
    nke[i] = fmaxf(sqrtf(fmaxf(dke + 2.f * ve * bki + N * bki * bki, 0.f)), 1e-12f);
    nki[i] = fmaxf(sqrtf(fmaxf(dki + 2.f * vi * bki + N * bki * bki, 0.f)), 1e-12f);
  }
  __syncthreads();
  int o = tid >> 2, jg = (tid & 3) * 16;
  for (int variant = 0; variant < 2; ++variant) {
    if (tid < 64) {
      int i = tid, h = i >> 3;
      const float* qrow = QK + (b * 2 + variant) * 4096 + i * 64;
      const float* nk = variant ? nki : nke;
      const float* vx = variant ? vxi : vxe;
      float t = temp[h];
      float bqi = bq[i];
      float lg[8];
      float mx = -1e30f;
#pragma unroll
      for (int d = 0; d < 8; ++d) {
        int j = h * 8 + d;
        float val = qrow[j] + u[i] * bk[j] + bqi * vx[j] + 65536.f * bqi * bk[j];
        val = val / (nq[i] * nk[j]) * t;
        lg[d] = val;
        mx = fmaxf(mx, val);
      }
      float se = 0;
#pragma unroll
      for (int d = 0; d < 8; ++d) { lg[d] = expf(lg[d] - mx); se += lg[d]; }
      float inv = 1.f / se;
#pragma unroll
      for (int d = 0; d < 8; ++d) attn[i][d] = lg[d] * inv;
    }
    __syncthreads();
#pragma unroll
    for (int jj = 0; jj < 16; ++jj) {
      int j = jg + jj, h = j >> 3, d = j & 7;
      float s = 0;
#pragma unroll
      for (int c = 0; c < 8; ++c) s += wo[o * 64 + h * 8 + c] * attn[h * 8 + c][d];
      Gm[o][j] = s;
    }
    __syncthreads();
    float acc[16] = {0};
    for (int m = 0; m < 64; ++m) {
      float gm = Gm[o][m];
      const float* wr = wv + m * 64 + jg;
#pragma unroll
      for (int jj = 0; jj < 16; ++jj) acc[jj] = fmaf(gm, wr[jj], acc[jj]);
    }
    float* go = G + ((long)(b * 2 + variant)) * 4096 + o * 64 + jg;
#pragma unroll
    for (int jj = 0; jj < 16; ++jj) go[jj] = acc[jj];
    __syncthreads();
  }
}

// ---------------- K3: fused = [Gv_e*x_i ; Gv_e*x_e ; Gv_i*x_i] ----------------
__global__ __launch_bounds__(256) void k3_fused(const float* __restrict__ xi_g,
                                                const float* __restrict__ xe_g,
                                                const float* __restrict__ G,
                                                __hip_bfloat16* __restrict__ fused) {
  int b = blockIdx.y;
  int px = blockIdx.x * 256 + threadIdx.x;
  const float* xi = xi_g + (long)b * 64 * NP + px;
  const float* xe = xe_g + (long)b * 64 * NP + px;
  float vi[64], ve[64];
#pragma unroll
  for (int c = 0; c < 64; ++c) vi[c] = xi[(long)c * NP];
#pragma unroll
  for (int c = 0; c < 64; ++c) ve[c] = xe[(long)c * NP];
  const float* Ge = G + (long)b * 2 * 4096;
  const float* Gi = Ge + 4096;
  __hip_bfloat16* out = fused + (long)b * 192 * NP + px;
  for (int oc = 0; oc < 64; ++oc) {
    const float* re = Ge + oc * 64;
    const float* ri = Gi + oc * 64;
    float a0 = 0, a1 = 0, a2 = 0;
#pragma unroll
    for (int c = 0; c < 64; ++c) {
      float w = re[c];
      a0 = fmaf(w, vi[c], a0);
      a1 = fmaf(w, ve[c], a1);
      a2 = fmaf(ri[c], vi[c], a2);
    }
    out[(long)oc * NP]         = __float2bfloat16(a0);
    out[(long)(64 + oc) * NP]  = __float2bfloat16(a1);
    out[(long)(128 + oc) * NP] = __float2bfloat16(a2);
  }
}

// ---------------- K4: conv3x3 reflect, 192 -> 128 (w_init||w1) + BN stat partials ----------------
__global__ __launch_bounds__(256, 2) void k4_conva(const __hip_bfloat16* __restrict__ fused,
                                                   const float* __restrict__ wcat,
                                                   __hip_bfloat16* __restrict__ yout,
                                                   float* __restrict__ statp) {
  __shared__ unsigned short inlds[3 * 192 * 36];
  __shared__ float wlds[8 * 9 * 128];
  __shared__ float statlds[256];
  int tid = threadIdx.x;
  int ry = blockIdx.y;
  int b = ry >> 8, y = ry & 255;
  int x0 = blockIdx.x << 5;
  const unsigned short* fb = (const unsigned short*)fused + (long)b * 192 * NP;
  int r0 = (y - 1 < 0) ? 1 : y - 1;
  int r2 = (y + 1 > 255) ? 254 : y + 1;
  int rows[3] = {r0, y, r2};
  for (int i = tid; i < 3 * 192 * 34; i += 256) {
    int r = i / 6528;
    int rem = i - r * 6528;
    int c = rem / 34;
    int j = rem - c * 34;
    int gx = x0 - 1 + j;
    gx = gx < 0 ? 1 : (gx > 255 ? 254 : gx);
    inlds[(r * 192 + c) * 36 + j] = fb[(long)c * NP + rows[r] * 256 + gx];
  }
  int oclane = tid & 31, pxlane = tid >> 5;
  int o0 = oclane * 4, p0 = pxlane * 4;
  float acc[4][4] = {{0.f}};
  for (int chunk = 0; chunk < 24; ++chunk) {
    __syncthreads();
    for (int i = tid; i < 2304; i += 256) {
      int c = i / 288;
      int rem = i - c * 288;
      int t = rem >> 5;
      int og = rem & 31;
      *(float4*)&wlds[(c * 9 + t) * 128 + og * 4] =
          *(const float4*)&wcat[(((chunk * 8 + c) * 9) + t) * 128 + og * 4];
    }
    __syncthreads();
#pragma unroll
    for (int cc = 0; cc < 8; ++cc) {
      int c = chunk * 8 + cc;
      float win[3][6];
#pragma unroll
      for (int r = 0; r < 3; ++r) {
        const unsigned short* bp = &inlds[(r * 192 + c) * 36 + p0];
        ushort4 ua = *(const ushort4*)bp;
        ushort2 ub = *(const ushort2*)(bp + 4);
        win[r][0] = b2f(ua.x); win[r][1] = b2f(ua.y); win[r][2] = b2f(ua.z);
        win[r][3] = b2f(ua.w); win[r][4] = b2f(ub.x); win[r][5] = b2f(ub.y);
      }
      float wv4[9][4];
#pragma unroll
      for (int t = 0; t < 9; ++t) {
        float4 w = *(const float4*)&wlds[(cc * 9 + t) * 128 + o0];
        wv4[t][0] = w.x; wv4[t][1] = w.y; wv4[t][2] = w.z; wv4[t][3] = w.w;
      }
#pragma unroll
      for (int ky = 0; ky < 3; ++ky)
#pragma unroll
        for (int kx = 0; kx < 3; ++kx)
#pragma unroll
          for (int oi = 0; oi < 4; ++oi)
#pragma unroll
            for (int pi = 0; pi < 4; ++pi)
              acc[oi][pi] = fmaf(wv4[ky * 3 + kx][oi], win[ky][pi + kx], acc[oi][pi]);
    }
  }
  statlds[tid] = 0.f;
  __syncthreads();
  __hip_bfloat16* yo = yout + (long)b * 128 * NP + (long)y * 256 + x0 + p0;
#pragma unroll
  for (int oi = 0; oi < 4; ++oi) {
    float s1 = 0, s2 = 0;
#pragma unroll
    for (int pi = 0; pi < 4; ++pi) {
      float v = acc[oi][pi];
      s1 += v;
      s2 += v * v;
      yo[(long)(o0 + oi) * NP + pi] = __float2bfloat16(v);
    }
    atomicAdd(&statlds[(o0 + oi) * 2], s1);
    atomicAdd(&statlds[(o0 + oi) * 2 + 1], s2);
  }
  __syncthreads();
  int blkid = blockIdx.y * 8 + blockIdx.x;
  statp[(long)blkid * 256 + tid] = statlds[tid];
}

// ---------------- K5a/K5b: BN stat reduce (conv A) ----------------
__global__ __launch_bounds__(256) void k5a(const float* __restrict__ statp, float* __restrict__ p2) {
  int rblk = blockIdx.x, tid = threadIdx.x;
  float s = 0;
  for (int k = 0; k < 32; ++k) s += statp[(long)(rblk * 32 + k) * 256 + tid];
  p2[rblk * 256 + tid] = s;
}

__global__ __launch_bounds__(256) void k5b(const float* __restrict__ p2,
                                           const float* __restrict__ g_init,
                                           const float* __restrict__ be_init,
                                           const float* __restrict__ g1,
                                           const float* __restrict__ be1,
                                           float* __restrict__ bnA) {
  int tid = threadIdx.x;
  float s = 0;
  for (int k = 0; k < 128; ++k) s += p2[k * 256 + tid];
  __shared__ float sm[256];
  sm[tid] = s;
  __syncthreads();
  if (tid < 128) {
    int oc = tid;
    float mean = sm[oc * 2] * (1.f / 131072.f);
    float var = sm[oc * 2 + 1] * (1.f / 131072.f) - mean * mean;
    float g  = oc < 64 ? g_init[oc] : g1[oc - 64];
    float be = oc < 64 ? be_init[oc] : be1[oc - 64];
    float sc = g * rsqrtf(fmaxf(var, 0.f) + 1e-5f);
    bnA[oc * 2] = sc;
    bnA[oc * 2 + 1] = be - mean * sc;
  }
}

// ---------------- K6: conv3x3 reflect, relu(bn1(y1)) -> 64 + stat partials ----------------
__global__ __launch_bounds__(256, 2) void k6_convb(const __hip_bfloat16* __restrict__ yws,
                                                   const float* __restrict__ w2t,
                                                   const float* __restrict__ bnA,
                                                   __hip_bfloat16* __restrict__ y2,
                                                   float* __restrict__ statp) {
  __shared__ float inlds[3 * 64 * 36];
  __shared__ float wlds[16 * 9 * 64];
  __shared__ float statlds[128];
  int tid = threadIdx.x;
  int ry = blockIdx.y;
  int b = ry >> 8, y = ry & 255;
  int x0 = blockIdx.x << 5;
  const __hip_bfloat16* yb = yws + ((long)b * 128 + 64) * NP;
  int r0 = (y - 1 < 0) ? 1 : y - 1;
  int r2 = (y + 1 > 255) ? 254 : y + 1;
  int rows[3] = {r0, y, r2};
  for (int i = tid; i < 3 * 64 * 34; i += 256) {
    int r = i / 2176;
    int rem = i - r * 2176;
    int c = rem / 34;
    int j = rem - c * 34;
    int gx = x0 - 1 + j;
    gx = gx < 0 ? 1 : (gx > 255 ? 254 : gx);
    float v = (float)yb[(long)c * NP + rows[r] * 256 + gx];
    v = fmaxf(fmaf(v, bnA[(64 + c) * 2], bnA[(64 + c) * 2 + 1]), 0.f);
    inlds[(r * 64 + c) * 36 + j] = v;
  }
  int oclane = tid & 15, pxlane = tid >> 4;
  int o0 = oclane * 4, p0 = pxlane * 2;
  float acc[4][2] = {{0.f}};
  for (int chunk = 0; chunk < 4; ++chunk) {
    __syncthreads();
    for (int i = tid; i < 2304; i += 256) {
      int c = i / 144;
      int rem = i - c * 144;
      int t = rem >> 4;
      int og = rem & 15;
      *(float4*)&wlds[(c * 9 + t) * 64 + og * 4] =
          *(const float4*)&w2t[(((chunk * 16 + c) * 9) + t) * 64 + og * 4];
    }
    __syncthreads();
#pragma unroll
    for (int cc = 0; cc < 16; ++cc) {
      int c = chunk * 16 + cc;
      float win[3][4];
#pragma unroll
      for (int r = 0; r < 3; ++r) {
        const float* bp = &inlds[(r * 64 + c) * 36 + p0];
        float2 wa = *(const float2*)bp;
        float2 wb = *(const float2*)(bp + 2);
        win[r][0] = wa.x; win[r][1] = wa.y; win[r][2] = wb.x; win[r][3] = wb.y;
      }
      float wv4[9][4];
#pragma unroll
      for (int t = 0; t < 9; ++t) {
        float4 w = *(const float4*)&wlds[(cc * 9 + t) * 64 + o0];
        wv4[t][0] = w.x; wv4[t][1] = w.y; wv4[t][2] = w.z; wv4[t][3] = w.w;
      }
#pragma unroll
      for (int ky = 0; ky < 3; ++ky)
#pragma unroll
        for (int kx = 0; kx < 3; ++kx)
#pragma unroll
          for (int oi = 0; oi < 4; ++oi)
#pragma unroll
            for (int pi = 0; pi < 2; ++pi)
              acc[oi][pi] = fmaf(wv4[ky * 3 + kx][oi], win[ky][pi + kx], acc[oi][pi]);
    }
  }
  if (tid < 128) statlds[tid] = 0.f;
  __syncthreads();
  __hip_bfloat16* yo = y2 + (long)b * 64 * NP + (long)y * 256 + x0 + p0;
#pragma unroll
  for (int oi = 0; oi < 4; ++oi) {
    float s1 = 0, s2 = 0;
#pragma unroll
    for (int pi = 0; pi < 2; ++pi) {
      float v = acc[oi][pi];
      s1 += v;
      s2 += v * v;
      yo[(long)(o0 + oi) * NP + pi] = __float2bfloat16(v);
    }
    atomicAdd(&statlds[(o0 + oi) * 2], s1);
    atomicAdd(&statlds[(o0 + oi) * 2 + 1], s2);
  }
  __syncthreads();
  int blkid = blockIdx.y * 8 + blockIdx.x;
  if (tid < 128) statp[(long)blkid * 128 + tid] = statlds[tid];
}

// ---------------- K7a/K7b: BN stat reduce (conv B) ----------------
__global__ __launch_bounds__(128) void k7a(const float* __restrict__ statp, float* __restrict__ p2) {
  int rblk = blockIdx.x, tid = threadIdx.x;
  float s = 0;
  for (int k = 0; k < 32; ++k) s += statp[(long)(rblk * 32 + k) * 128 + tid];
  p2[rblk * 128 + tid] = s;
}

__global__ __launch_bounds__(128) void k7b(const float* __restrict__ p2,
                                           const float* __restrict__ g2,
                                           const float* __restrict__ be2,
                                           float* __restrict__ bnB) {
  int tid = threadIdx.x;
  float s = 0;
  for (int k = 0; k < 128; ++k) s += p2[k * 128 + tid];
  __shared__ float sm[128];
  sm[tid] = s;
  __syncthreads();
  if (tid < 64) {
    int oc = tid;
    float mean = sm[oc * 2] * (1.f / 131072.f);
    float var = sm[oc * 2 + 1] * (1.f / 131072.f) - mean * mean;
    float sc = g2[oc] * rsqrtf(fmaxf(var, 0.f) + 1e-5f);
    bnB[oc * 2] = sc;
    bnB[oc * 2 + 1] = be2[oc] - mean * sc;
  }
}

// ---------------- K8: out = relu(relu(bn_init(y_init)) + bn2(y2)) ----------------
__global__ __launch_bounds__(256) void k8_final(const __hip_bfloat16* __restrict__ yws,
                                                const __hip_bfloat16* __restrict__ y2,
                                                const float* __restrict__ bnA,
                                                const float* __restrict__ bnB,
                                                float* __restrict__ out) {
  int idx = blockIdx.x * 256 + threadIdx.x;  // 2*64*65536 total
  int bc = idx >> 16;
  int c = bc & 63, b = bc >> 6;
  long px = idx & 65535;
  float yi = (float)yws[((long)b * 128 + c) * NP + px];
  float ini = fmaxf(fmaf(yi, bnA[c * 2], bnA[c * 2 + 1]), 0.f);
  float y2v = (float)y2[idx];
  float cb = fmaf(y2v, bnB[c * 2], bnB[c * 2 + 1]);
  out[idx] = fmaxf(ini + cb, 0.f);
}

extern "C" void kernel_launch(void* const* d_in, const int* in_sizes, int n_in,
                              void* d_out, int out_size, void* d_ws, size_t ws_size,
                              hipStream_t stream) {
  if (ws_size < (size_t)WS_NEED) return;  // insufficient scratch -> fail loudly via validation
  const float* x_i  = (const float*)d_in[0];
  const float* x_e  = (const float*)d_in[1];
  const float* y    = (const float*)d_in[2];
  const float* temp = (const float*)d_in[3];
  const float* wq   = (const float*)d_in[4];
  const float* bq   = (const float*)d_in[5];
  const float* wk   = (const float*)d_in[6];
  const float* bk   = (const float*)d_in[7];
  const float* wv   = (const float*)d_in[8];
  const float* wo   = (const float*)d_in[10];
  const float* w_init = (const float*)d_in[12];
  const float* g_init = (const float*)d_in[14];
  const float* be_init= (const float*)d_in[15];
  const float* w1   = (const float*)d_in[16];
  const float* g1   = (const float*)d_in[18];
  const float* be1  = (const float*)d_in[19];
  const float* w2   = (const float*)d_in[20];
  const float* g2   = (const float*)d_in[22];
  const float* be2  = (const float*)d_in[23];

  char* ws = (char*)d_ws;
  float* gp    = (float*)(ws + WSO_GP);
  float* Mw    = (float*)(ws + WSO_M);
  float* Sw    = (float*)(ws + WSO_S);
  float* Pw    = (float*)(ws + WSO_P);
  float* QKw   = (float*)(ws + WSO_QK);
  float* Gw    = (float*)(ws + WSO_G);
  float* wkT   = (float*)(ws + WSO_WKT);
  float* wcat  = (float*)(ws + WSO_WCAT);
  float* w2t   = (float*)(ws + WSO_W2T);
  __hip_bfloat16* fused = (__hip_bfloat16*)(ws + WSO_FUSED);
  __hip_bfloat16* yws   = (__hip_bfloat16*)(ws + WSO_Y);
  float* statA = (float*)(ws + WSO_STATA);
  float* p2A   = (float*)(ws + WSO_P2A);
  float* bnA   = (float*)(ws + WSO_BNA);
  __hip_bfloat16* y2 = (__hip_bfloat16*)(ws + WSO_Y2);
  float* statB = (float*)(ws + WSO_STATB);
  float* p2B   = (float*)(ws + WSO_P2B);
  float* bnB   = (float*)(ws + WSO_BNB);
  float* out   = (float*)d_out;

  hipLaunchKernelGGL(k0_prep, dim3(1024), dim3(256), 0, stream,
                     w_init, w1, w2, wk, wcat, w2t, wkT);
  hipLaunchKernelGGL(k1_gram, dim3(128, 2), dim3(256), 0, stream, x_i, x_e, y, gp);
  hipLaunchKernelGGL(k1_reduce, dim3(162), dim3(256), 0, stream, gp, Mw, Sw);
  hipLaunchKernelGGL(k2a, dim3(5, 2), dim3(256), 0, stream, wq, wk, Mw, Pw);
  hipLaunchKernelGGL(k2b, dim3(2, 2), dim3(256), 0, stream, Pw, wkT, QKw);
  hipLaunchKernelGGL(k2c, dim3(2), dim3(256), 0, stream,
                     Pw, QKw, Sw, wq, wk, wv, wo, bq, bk, temp, Gw);
  hipLaunchKernelGGL(k3_fused, dim3(256, 2), dim3(256), 0, stream, x_i, x_e, Gw, fused);
  hipLaunchKernelGGL(k4_conva, dim3(8, 512), dim3(256), 0, stream, fused, wcat, yws, statA);
  hipLaunchKernelGGL(k5a, dim3(128), dim3(256), 0, stream, statA, p2A);
  hipLaunchKernelGGL(k5b, dim3(1), dim3(256), 0, stream, p2A, g_init, be_init, g1, be1, bnA);
  hipLaunchKernelGGL(k6_convb, dim3(8, 512), dim3(256), 0, stream, yws, w2t, bnA, y2, statB);
  hipLaunchKernelGGL(k7a, dim3(128), dim3(128), 0, stream, statB, p2B);
  hipLaunchKernelGGL(k7b, dim3(1), dim3(128), 0, stream, p2B, g2, be2, bnB);
  hipLaunchKernelGGL(k8_final, dim3(32768), dim3(256), 0, stream, yws, y2, bnA, bnB, out);
}

// Round 2
// 418.711 us; speedup vs baseline: 5.5391x; 5.5391x over previous
//
#include <hip/hip_runtime.h>
#include <hip/hip_bf16.h>

#define DI __device__ __forceinline__

typedef __attribute__((ext_vector_type(8))) short bh8;
typedef __attribute__((ext_vector_type(4))) float f4;

constexpr int  NP        = 65536;              // H*W per batch
constexpr long GP_STRIDE = 20672;              // 5*4096 + 192

// workspace byte offsets
constexpr long WSO_GP    = 0;                                  // [2][128][GP_STRIDE] f32
constexpr long WSO_M     = WSO_GP    + 2L*128*GP_STRIDE*4;     // [2][5][4096] f32
constexpr long WSO_S     = WSO_M     + 2L*5*4096*4;            // [2][192] f32
constexpr long WSO_P     = WSO_S     + 2L*192*4;               // [2][5][4096] f32
constexpr long WSO_QK    = WSO_P     + 2L*5*4096*4;            // [2][2][4096] f32
constexpr long WSO_G     = WSO_QK    + 2L*2*4096*4;            // [2][2][4096] f32
constexpr long WSO_WKT   = WSO_G     + 2L*2*4096*4;            // [4096] f32
constexpr long WSO_WBA   = WSO_WKT   + 4096L*4;                // [54][128][32] bf16 (swizzled)
constexpr long WSO_WBB   = WSO_WBA   + 221184L*2;              // [18][64][32] bf16 (swizzled)
constexpr long WSO_FUSED = WSO_WBB   + 36864L*2;               // [2][NP][192] bf16 pixel-major
constexpr long WSO_Y     = WSO_FUSED + 2L*NP*192*2;            // [2][NP][128] bf16 pixel-major
constexpr long WSO_STATA = WSO_Y     + 2L*NP*128*2;            // [1024][256] f32
constexpr long WSO_P2A   = WSO_STATA + 1024L*256*4;            // [128][256] f32
constexpr long WSO_BNA   = WSO_P2A   + 128L*256*4;             // [256] f32
constexpr long WSO_Y2    = WSO_BNA   + 256L*4;                 // [2][NP][64] bf16 pixel-major
constexpr long WSO_STATB = WSO_Y2    + 2L*NP*64*2;             // [1024][128] f32
constexpr long WSO_P2B   = WSO_STATB + 1024L*128*4;            // [128][128] f32
constexpr long WSO_BNB   = WSO_P2B   + 128L*128*4;             // [128] f32
constexpr long WS_NEED   = WSO_BNB   + 128L*4;

constexpr int AROWB = 136 * 128;   // bytes per row-strip in conv LDS (136 px * 128 B)
constexpr int ALDSB = 3 * AROWB;   // 52224

DI float b2f(unsigned short u) { return __uint_as_float(((unsigned)u) << 16); }
DI unsigned short f2b(float f) {
  __hip_bfloat16 h = __float2bfloat16(f);
  return *(unsigned short*)&h;
}
DI void gl_lds16(const void* g, void* l) {
  __builtin_amdgcn_global_load_lds(
      (const __attribute__((address_space(1))) unsigned int*)g,
      (__attribute__((address_space(3))) unsigned int*)l, 16, 0, 0);
}

// ---------------- K0: weight re-layouts (bf16, B^T, bank-swizzled) ----------------
__global__ __launch_bounds__(256) void k0_prep(const float* __restrict__ w_init,
                                               const float* __restrict__ w1,
                                               const float* __restrict__ w2,
                                               const float* __restrict__ wk,
                                               unsigned short* __restrict__ wBA,
                                               unsigned short* __restrict__ wBB,
                                               float* __restrict__ wkT) {
  int i = blockIdx.x * 256 + threadIdx.x;
  if (i < 221184) {                 // conv A weights: step = chunk*18 + tap*2 + s
    int step = i >> 12;
    int rem = i & 4095;
    int oc = rem >> 5, kk = rem & 31;
    int chunk = step / 18, r2 = step % 18;
    int tap = r2 >> 1, s = r2 & 1;
    int c = chunk * 64 + s * 32 + kk;
    float v = (oc < 64) ? w_init[(oc * 192 + c) * 9 + tap]
                        : w1[((oc - 64) * 192 + c) * 9 + tap];
    wBA[(step << 12) + (oc << 5) + (kk ^ ((oc & 3) << 3))] = f2b(v);
  } else if (i < 258048) {          // conv B weights: step = tap*2 + s
    int j = i - 221184;
    int step = j >> 11;
    int rem = j & 2047;
    int oc = rem >> 5, kk = rem & 31;
    int tap = step >> 1, s = step & 1;
    int c = s * 32 + kk;
    wBB[(step << 11) + (oc << 5) + (kk ^ ((oc & 3) << 3))] = f2b(w2[(oc * 64 + c) * 9 + tap]);
  } else {
    int j = i - 258048;
    int kkk = j >> 6, oo = j & 63;
    wkT[j] = wk[oo * 64 + kkk];
  }
}

// ---------------- K1: per-b Gram matrices ----------------
#define OUTER4(ACC, A, Bv)                                                     \
  ACC[0]  = fmaf(A.x, Bv.x, ACC[0]);  ACC[1]  = fmaf(A.x, Bv.y, ACC[1]);       \
  ACC[2]  = fmaf(A.x, Bv.z, ACC[2]);  ACC[3]  = fmaf(A.x, Bv.w, ACC[3]);       \
  ACC[4]  = fmaf(A.y, Bv.x, ACC[4]);  ACC[5]  = fmaf(A.y, Bv.y, ACC[5]);       \
  ACC[6]  = fmaf(A.y, Bv.z, ACC[6]);  ACC[7]  = fmaf(A.y, Bv.w, ACC[7]);       \
  ACC[8]  = fmaf(A.z, Bv.x, ACC[8]);  ACC[9]  = fmaf(A.z, Bv.y, ACC[9]);       \
  ACC[10] = fmaf(A.z, Bv.z, ACC[10]); ACC[11] = fmaf(A.z, Bv.w, ACC[11]);      \
  ACC[12] = fmaf(A.w, Bv.x, ACC[12]); ACC[13] = fmaf(A.w, Bv.y, ACC[13]);      \
  ACC[14] = fmaf(A.w, Bv.z, ACC[14]); ACC[15] = fmaf(A.w, Bv.w, ACC[15]);

__global__ __launch_bounds__(256) void k1_gram(const float* __restrict__ xi,
                                               const float* __restrict__ xe,
                                               const float* __restrict__ yy,
                                               float* __restrict__ gp) {
  __shared__ float st[3][64][68];
  int tid = threadIdx.x;
  int blk = blockIdx.x, b = blockIdx.y;
  const float* src0 = yy + (long)b * 64 * NP;
  const float* src1 = xe + (long)b * 64 * NP;
  const float* src2 = xi + (long)b * 64 * NP;
  int tc = tid & 15, td = tid >> 4;
  float acc0[16] = {0}, acc1[16] = {0}, acc2[16] = {0}, acc3[16] = {0}, acc4[16] = {0};
  float sumreg = 0.f;
  int sc_t = tid >> 6, sc_c = tid & 63;

  for (int ch = 0; ch < 8; ++ch) {
    int n0 = blk * 512 + ch * 64;
    __syncthreads();
    for (int i = tid; i < 3072; i += 256) {
      int t = i >> 10, r = i & 1023, c = r >> 4, j = r & 15;
      const float* s = (t == 0 ? src0 : (t == 1 ? src1 : src2)) + (long)c * NP + n0 + j * 4;
      float4 v = *(const float4*)s;
      st[t][j * 4 + 0][c] = v.x;
      st[t][j * 4 + 1][c] = v.y;
      st[t][j * 4 + 2][c] = v.z;
      st[t][j * 4 + 3][c] = v.w;
    }
    __syncthreads();
#pragma unroll 4
    for (int n = 0; n < 64; ++n) {
      float4 a0 = *(const float4*)&st[0][n][tc * 4];
      float4 a1 = *(const float4*)&st[1][n][tc * 4];
      float4 a2 = *(const float4*)&st[2][n][tc * 4];
      float4 b0 = *(const float4*)&st[0][n][td * 4];
      float4 b1 = *(const float4*)&st[1][n][td * 4];
      float4 b2 = *(const float4*)&st[2][n][td * 4];
      OUTER4(acc0, a0, b1)
      OUTER4(acc1, a0, b2)
      OUTER4(acc2, a0, b0)
      OUTER4(acc3, a1, b1)
      OUTER4(acc4, a2, b2)
    }
    if (tid < 192) {
#pragma unroll
      for (int n = 0; n < 64; ++n) sumreg += st[sc_t][n][sc_c];
    }
  }
  float* out = gp + ((long)b * 128 + blk) * GP_STRIDE;
#define STOREG(g, ACC)                                                          \
  {                                                                             \
    _Pragma("unroll") for (int oi = 0; oi < 4; ++oi) {                          \
      float4 v = make_float4(ACC[oi * 4 + 0], ACC[oi * 4 + 1],                  \
                             ACC[oi * 4 + 2], ACC[oi * 4 + 3]);                 \
      *(float4*)&out[(g) * 4096 + (tc * 4 + oi) * 64 + td * 4] = v;             \
    }                                                                           \
  }
  STOREG(0, acc0) STOREG(1, acc1) STOREG(2, acc2) STOREG(3, acc3) STOREG(4, acc4)
  if (tid < 192) out[5 * 4096 + tid] = sumreg;
}

// ---------------- K1r: reduce Gram partials ----------------
__global__ __launch_bounds__(256) void k1_reduce(const float* __restrict__ gp,
                                                 float* __restrict__ M,
                                                 float* __restrict__ S) {
  int i = blockIdx.x * 256 + threadIdx.x;
  if (i >= 2 * GP_STRIDE) return;
  int b = i / GP_STRIDE, o = i % GP_STRIDE;
  const float* p = gp + (long)b * 128 * GP_STRIDE + o;
  float s = 0;
  for (int k = 0; k < 128; ++k) s += p[(long)k * GP_STRIDE];
  if (o < 20480) M[b * 20480 + o] = s;
  else           S[b * 192 + (o - 20480)] = s;
}

// ---------------- K2a: P_g = W * M_g ----------------
__global__ __launch_bounds__(256) void k2a(const float* __restrict__ wq,
                                           const float* __restrict__ wk,
                                           const float* __restrict__ M,
                                           float* __restrict__ P) {
  int b = blockIdx.y, g = blockIdx.x;
  const float* W = (g < 3) ? wq : wk;
  const float* Mg = M + b * 20480 + g * 4096;
  float* Pg = P + b * 20480 + g * 4096;
  int tid = threadIdx.x;
  int i = tid >> 2, jg = (tid & 3) * 16;
  float acc[16] = {0};
  for (int k = 0; k < 64; ++k) {
    float w = W[i * 64 + k];
    const float* mrow = Mg + k * 64 + jg;
#pragma unroll
    for (int j = 0; j < 16; ++j) acc[j] = fmaf(w, mrow[j], acc[j]);
  }
#pragma unroll
  for (int j = 0; j < 16; ++j) Pg[i * 64 + jg + j] = acc[j];
}

// ---------------- K2b: QK = P{0,1} * Wk^T ----------------
__global__ __launch_bounds__(256) void k2b(const float* __restrict__ P,
                                           const float* __restrict__ wkT,
                                           float* __restrict__ QK) {
  int b = blockIdx.y, v = blockIdx.x;
  const float* Pg = P + b * 20480 + v * 4096;
  float* out = QK + (b * 2 + v) * 4096;
  int tid = threadIdx.x;
  int i = tid >> 2, jg = (tid & 3) * 16;
  float acc[16] = {0};
  for (int k = 0; k < 64; ++k) {
    float w = Pg[i * 64 + k];
    const float* mrow = wkT + k * 64 + jg;
#pragma unroll
    for (int j = 0; j < 16; ++j) acc[j] = fmaf(w, mrow[j], acc[j]);
  }
#pragma unroll
  for (int j = 0; j < 16; ++j) out[i * 64 + jg + j] = acc[j];
}

// ---------------- K2c: norms, softmax, Gv = wo*BD(attn)*Wv ----------------
__global__ __launch_bounds__(256) void k2c(const float* __restrict__ P,
                                           const float* __restrict__ QK,
                                           const float* __restrict__ Ssum,
                                           const float* __restrict__ wq,
                                           const float* __restrict__ wk,
                                           const float* __restrict__ wv,
                                           const float* __restrict__ wo,
                                           const float* __restrict__ bq,
                                           const float* __restrict__ bk,
                                           const float* __restrict__ temp,
                                           float* __restrict__ G) {
  int b = blockIdx.x, tid = threadIdx.x;
  __shared__ float u[64], vxe[64], vxi[64], nq[64], nke[64], nki[64];
  __shared__ float attn[64][8];
  __shared__ float Gm[64][64];
  if (tid < 64) {
    int i = tid;
    float uu = 0, ve = 0, vi = 0, dq = 0, dke = 0, dki = 0;
    const float* p2 = P + b * 20480 + 2 * 4096 + i * 64;
    const float* p3 = P + b * 20480 + 3 * 4096 + i * 64;
    const float* p4 = P + b * 20480 + 4 * 4096 + i * 64;
    const float* sy = Ssum + b * 192;
    const float* sxe = sy + 64;
    const float* sxi = sy + 128;
#pragma unroll 8
    for (int k = 0; k < 64; ++k) {
      float wqk = wq[i * 64 + k], wkk = wk[i * 64 + k];
      uu += wqk * sy[k];  ve += wkk * sxe[k];  vi += wkk * sxi[k];
      dq += p2[k] * wqk;  dke += p3[k] * wkk;  dki += p4[k] * wkk;
    }
    u[i] = uu; vxe[i] = ve; vxi[i] = vi;
    const float N = 65536.f;
    float bqi = bq[i], bki = bk[i];
    nq[i]  = fmaxf(sqrtf(fmaxf(dq  + 2.f * uu * bqi + N * bqi * bqi, 0.f)), 1e-12f);
    nke[i] = fmaxf(sqrtf(fmaxf(dke + 2.f * ve * bki + N * bki * bki, 0.f)), 1e-12f);
    nki[i] = fmaxf(sqrtf(fmaxf(dki + 2.f * vi * bki + N * bki * bki, 0.f)), 1e-12f);
  }
  __syncthreads();
  int o = tid >> 2, jg = (tid & 3) * 16;
  for (int variant = 0; variant < 2; ++variant) {
    if (tid < 64) {
      int i = tid, h = i >> 3;
      const float* qrow = QK + (b * 2 + variant) * 4096 + i * 64;
      const float* nk = variant ? nki : nke;
      const float* vx = variant ? vxi : vxe;
      float t = temp[h];
      float bqi = bq[i];
      float lg[8];
      float mx = -1e30f;
#pragma unroll
      for (int d = 0; d < 8; ++d) {
        int j = h * 8 + d;
        float val = qrow[j] + u[i] * bk[j] + bqi * vx[j] + 65536.f * bqi * bk[j];
        val = val / (nq[i] * nk[j]) * t;
        lg[d] = val;
        mx = fmaxf(mx, val);
      }
      float se = 0;
#pragma unroll
      for (int d = 0; d < 8; ++d) { lg[d] = expf(lg[d] - mx); se += lg[d]; }
      float inv = 1.f / se;
#pragma unroll
      for (int d = 0; d < 8; ++d) attn[i][d] = lg[d] * inv;
    }
    __syncthreads();
#pragma unroll
    for (int jj = 0; jj < 16; ++jj) {
      int j = jg + jj, h = j >> 3, d = j & 7;
      float s = 0;
#pragma unroll
      for (int c = 0; c < 8; ++c) s += wo[o * 64 + h * 8 + c] * attn[h * 8 + c][d];
      Gm[o][j] = s;
    }
    __syncthreads();
    float acc[16] = {0};
    for (int m = 0; m < 64; ++m) {
      float gm = Gm[o][m];
      const float* wr = wv + m * 64 + jg;
#pragma unroll
      for (int jj = 0; jj < 16; ++jj) acc[jj] = fmaf(gm, wr[jj], acc[jj]);
    }
    float* go = G + ((long)(b * 2 + variant)) * 4096 + o * 64 + jg;
#pragma unroll
    for (int jj = 0; jj < 16; ++jj) go[jj] = acc[jj];
    __syncthreads();
  }
}

// ---------------- K3: fused = [Gv_e*x_i ; Gv_e*x_e ; Gv_i*x_i], pixel-major bf16 ----------------
__global__ __launch_bounds__(512) void k3_fused(const float* __restrict__ xi_g,
                                                const float* __restrict__ xe_g,
                                                const float* __restrict__ G,
                                                unsigned short* __restrict__ fused) {
  __shared__ float xt[2 * 64 * 66];                // [t][px][66]
  __shared__ float Gf[128 * 66];                   // [v*64+oc][66]
  __shared__ alignas(16) unsigned short ot[64 * 200];  // [px][200] (192 used)
  int tid = threadIdx.x;
  int b = blockIdx.y;
  int px0 = blockIdx.x * 64;

  for (int it = 0; it < 16; ++it) {
    int slot = it * 512 + tid;          // 8192 = 2*64*64
    int t = slot >> 12, rem = slot & 4095;
    int c = rem >> 6, px = rem & 63;
    const float* src = (t ? xe_g : xi_g) + ((long)b * 64 + c) * NP + px0 + px;
    xt[(t * 64 + px) * 66 + c] = *src;
  }
  const float* Gb = G + (long)b * 2 * 4096;
  for (int it = 0; it < 16; ++it) {
    int slot = it * 512 + tid;          // 8192
    Gf[(slot >> 6) * 66 + (slot & 63)] = Gb[slot];
  }
  __syncthreads();

  int g = tid >> 6, px = tid & 63;      // wave = oc-group (G reads broadcast)
  float a0[8] = {0.f}, a1[8] = {0.f}, a2[8] = {0.f};
  const float* xv = &xt[(0 * 64 + px) * 66];
  const float* xw = &xt[(1 * 64 + px) * 66];
  for (int c2 = 0; c2 < 32; ++c2) {
    float vix = xv[c2 * 2], viy = xv[c2 * 2 + 1];
    float vex = xw[c2 * 2], vey = xw[c2 * 2 + 1];
#pragma unroll
    for (int j = 0; j < 8; ++j) {
      int oc = g * 8 + j;
      float gex = Gf[oc * 66 + c2 * 2], gey = Gf[oc * 66 + c2 * 2 + 1];
      float gix = Gf[(64 + oc) * 66 + c2 * 2], giy = Gf[(64 + oc) * 66 + c2 * 2 + 1];
      a0[j] += gex * vix + gey * viy;
      a1[j] += gex * vex + gey * vey;
      a2[j] += gix * vix + giy * viy;
    }
  }
  bh8 p0, p1, p2;
#pragma unroll
  for (int j = 0; j < 8; ++j) {
    p0[j] = (short)f2b(a0[j]);
    p1[j] = (short)f2b(a1[j]);
    p2[j] = (short)f2b(a2[j]);
  }
  *(bh8*)&ot[px * 200 + g * 8]       = p0;
  *(bh8*)&ot[px * 200 + 64 + g * 8]  = p1;
  *(bh8*)&ot[px * 200 + 128 + g * 8] = p2;
  __syncthreads();

  unsigned short* fb = fused + ((long)b * NP + px0) * 192;
  for (int it = 0; it < 3; ++it) {
    int idx = it * 512 + tid;           // 1536 chunks of 16B
    int p = idx / 24, cc = idx % 24;
    f4 v = *(const f4*)&ot[p * 200 + cc * 8];
    *(f4*)((char*)(fb + (long)p * 192) + cc * 16) = v;
  }
}

// ---------------- K4: conv3x3 reflect 192->128 via MFMA + BN stat partials ----------------
__global__ __launch_bounds__(256, 2) void k4_mfma(const unsigned short* __restrict__ fused,
                                                  const unsigned short* __restrict__ wBA,
                                                  unsigned short* __restrict__ yout,
                                                  float* __restrict__ statp) {
  __shared__ alignas(16) char lds[ALDSB + 16384 + 1024];
  char* ldsB = lds + ALDSB;
  float* statf = (float*)(lds + ALDSB + 16384);

  int tid = threadIdx.x;
  int wave = tid >> 6, lane = tid & 63;
  int kc = lane >> 4, i16 = lane & 15;

  int bid = blockIdx.x;
  int blk = (bid & 7) * 128 + (bid >> 3);   // bijective XCD swizzle (1024 % 8 == 0)
  int b = blk >> 9, y = (blk >> 1) & 255, xt = blk & 1;
  int x0 = xt << 7;
  int rows[3] = {y > 0 ? y - 1 : 1, y, y < 255 ? y + 1 : 254};

  const unsigned short* fb = fused + (long)b * NP * 192;
  statf[tid] = 0.f;

  int wm = wave & 1, wn = wave >> 1;
  int m0 = wm * 64, n0 = wn * 64;

  f4 zero = {0.f, 0.f, 0.f, 0.f};
  f4 acc[4][4];
#pragma unroll
  for (int i = 0; i < 4; ++i)
#pragma unroll
    for (int j = 0; j < 4; ++j) acc[i][j] = zero;

  for (int ch = 0; ch < 3; ++ch) {
    __syncthreads();                        // protect A region reuse
    long ch0b = (long)ch * 128;             // byte offset within 384-B fused row
    // ---- stage A (3 rows x 136 px x 64ch), source pre-swizzled ----
#pragma unroll
    for (int it = 0; it < 13; ++it) {
      int base = (wave * 13 + it) << 10;
      if (base < ALDSB) {
        int slot = base + lane * 16;
        int row = slot / AROWB;
        int rr = slot - row * AROWB;
        int px = rr >> 7, cb = rr & 127;
        int pxl = px < 130 ? px : 129;
        int gx = x0 - 1 + pxl;
        gx = gx < 0 ? 1 : (gx > 255 ? 254 : gx);
        int cbs = cb ^ ((px & 7) << 4);
        const char* src = (const char*)(fb + (long)(rows[row] * 256 + gx) * 192) + ch0b + cbs;
        gl_lds16(src, lds + base);
      }
    }
    // ---- stage B step 0 of chunk ----
    {
      const char* wsrc = (const char*)wBA + (long)(ch * 18) * 8192;
#pragma unroll
      for (int it = 0; it < 2; ++it) {
        int base = (wave * 2 + it) << 10;
        gl_lds16(wsrc + base + lane * 16, ldsB + base);
      }
    }
    __syncthreads();

    for (int st = 0; st < 18; ++st) {
      int cur = st & 1;
      if (st < 17) {
        const char* wsrc = (const char*)wBA + (long)(ch * 18 + st + 1) * 8192;
#pragma unroll
        for (int it = 0; it < 2; ++it) {
          int base = (wave * 2 + it) << 10;
          gl_lds16(wsrc + base + lane * 16, ldsB + ((cur ^ 1) << 13) + base);
        }
      }
      int tap = st >> 1, s = st & 1;
      int kx = tap % 3, rowk = tap / 3;
      const char* arow = lds + rowk * AROWB;
      int cbb = s * 64 + kc * 16;
      bh8 af[4], bfr[4];
#pragma unroll
      for (int mf = 0; mf < 4; ++mf) {
        int pxl = kx + m0 + mf * 16 + i16;
        af[mf] = *(const bh8*)(arow + pxl * 128 + (cbb ^ ((pxl & 7) << 4)));
      }
      const char* bbuf = ldsB + (cur << 13);
#pragma unroll
      for (int nf = 0; nf < 4; ++nf) {
        int oc = n0 + nf * 16 + i16;
        bfr[nf] = *(const bh8*)(bbuf + oc * 64 + ((kc * 16) ^ ((oc & 3) << 4)));
      }
#pragma unroll
      for (int mf = 0; mf < 4; ++mf)
#pragma unroll
        for (int nf = 0; nf < 4; ++nf)
          acc[mf][nf] = __builtin_amdgcn_mfma_f32_16x16x32_bf16(af[mf], bfr[nf], acc[mf][nf], 0, 0, 0);
      __syncthreads();
    }
  }

  // ---- BN stat partials ----
#pragma unroll
  for (int nf = 0; nf < 4; ++nf) {
    float s1 = 0.f, s2 = 0.f;
#pragma unroll
    for (int mf = 0; mf < 4; ++mf)
#pragma unroll
      for (int r = 0; r < 4; ++r) {
        float v = acc[mf][nf][r];
        s1 += v; s2 += v * v;
      }
    s1 += __shfl_xor(s1, 16); s2 += __shfl_xor(s2, 16);
    s1 += __shfl_xor(s1, 32); s2 += __shfl_xor(s2, 32);
    if (lane < 16) {
      int oc = n0 + nf * 16 + i16;
      atomicAdd(&statf[oc * 2], s1);
      atomicAdd(&statf[oc * 2 + 1], s2);
    }
  }
  __syncthreads();
  // ---- transpose acc -> pixel-major bf16 (reuse A region, swizzled) ----
#pragma unroll
  for (int nf = 0; nf < 4; ++nf) {
    int oc2 = (n0 + nf * 16 + i16) * 2;
#pragma unroll
    for (int mf = 0; mf < 4; ++mf)
#pragma unroll
      for (int r = 0; r < 4; ++r) {
        int px = m0 + mf * 16 + kc * 4 + r;
        *(unsigned short*)(lds + px * 256 + (oc2 ^ ((px & 7) << 4))) = f2b(acc[mf][nf][r]);
      }
  }
  __syncthreads();
  unsigned short* yb = yout + (long)b * NP * 128;
#pragma unroll
  for (int it = 0; it < 8; ++it) {
    int slot = (it * 256 + tid) * 16;
    int px = slot >> 8, cb = slot & 255;
    int cbs = cb ^ ((px & 7) << 4);
    f4 v = *(const f4*)(lds + px * 256 + cbs);
    *(f4*)((char*)(yb + (long)(y * 256 + x0 + px) * 128) + cb) = v;
  }
  statp[(long)bid * 256 + tid] = statf[tid];
}

// ---------------- K5a/K5b: BN stat reduce (conv A) ----------------
__global__ __launch_bounds__(256) void k5a(const float* __restrict__ statp, float* __restrict__ p2) {
  int rblk = blockIdx.x, tid = threadIdx.x;
  float s = 0;
  for (int k = 0; k < 8; ++k) s += statp[(long)(rblk * 8 + k) * 256 + tid];
  p2[rblk * 256 + tid] = s;
}

__global__ __launch_bounds__(256) void k5b(const float* __restrict__ p2,
                                           const float* __restrict__ g_init,
                                           const float* __restrict__ be_init,
                                           const float* __restrict__ g1,
                                           const float* __restrict__ be1,
                                           float* __restrict__ bnA) {
  int tid = threadIdx.x;
  float s = 0;
  for (int k = 0; k < 128; ++k) s += p2[k * 256 + tid];
  __shared__ float sm[256];
  sm[tid] = s;
  __syncthreads();
  if (tid < 128) {
    int oc = tid;
    float mean = sm[oc * 2] * (1.f / 131072.f);
    float var = sm[oc * 2 + 1] * (1.f / 131072.f) - mean * mean;
    float g  = oc < 64 ? g_init[oc] : g1[oc - 64];
    float be = oc < 64 ? be_init[oc] : be1[oc - 64];
    float sc = g * rsqrtf(fmaxf(var, 0.f) + 1e-5f);
    bnA[oc * 2] = sc;
    bnA[oc * 2 + 1] = be - mean * sc;
  }
}

// ---------------- K6: conv3x3 reflect relu(bn1(y1)) -> 64 via MFMA + stats ----------------
__global__ __launch_bounds__(256, 2) void k6_mfma(const unsigned short* __restrict__ yws,
                                                  const unsigned short* __restrict__ wBB,
                                                  const float* __restrict__ bnA,
                                                  unsigned short* __restrict__ y2,
                                                  float* __restrict__ statp) {
  __shared__ alignas(16) char lds[ALDSB + 8192 + 512];
  char* ldsB = lds + ALDSB;
  float* statf = (float*)(lds + ALDSB + 8192);

  int tid = threadIdx.x;
  int wave = tid >> 6, lane = tid & 63;
  int kc = lane >> 4, i16 = lane & 15;

  int bid = blockIdx.x;
  int blk = (bid & 7) * 128 + (bid >> 3);
  int b = blk >> 9, y = (blk >> 1) & 255, xt = blk & 1;
  int x0 = xt << 7;
  int rows[3] = {y > 0 ? y - 1 : 1, y, y < 255 ? y + 1 : 254};

  if (tid < 128) statf[tid] = 0.f;

  // per-thread channel group for reg-staged BN+relu transform
  int c0 = (tid & 7) * 8;
  float sc[8], bi[8];
#pragma unroll
  for (int e = 0; e < 8; ++e) {
    int cc = 64 + c0 + e;
    sc[e] = bnA[cc * 2];
    bi[e] = bnA[cc * 2 + 1];
  }
  const unsigned short* yb = yws + (long)b * NP * 128;
  int pbase = tid >> 3;
  for (int r = 0; r < 13; ++r) {
    int p = pbase + r * 32;
    if (p < 408) {
      int row = p / 136, pxs = p - row * 136;
      int pxl = pxs < 130 ? pxs : 129;
      int gx = x0 - 1 + pxl;
      gx = gx < 0 ? 1 : (gx > 255 ? 254 : gx);
      const unsigned short* src = yb + (long)(rows[row] * 256 + gx) * 128 + 64 + c0;
      bh8 v = *(const bh8*)src;
      bh8 o;
#pragma unroll
      for (int e = 0; e < 8; ++e) {
        float f = fmaxf(b2f((unsigned short)v[e]) * sc[e] + bi[e], 0.f);
        o[e] = (short)f2b(f);
      }
      *(bh8*)(lds + p * 128 + ((c0 * 2) ^ ((pxs & 7) << 4))) = o;
    }
  }
  // B prefetch step 0
  {
    int base = wave << 10;
    gl_lds16((const char*)wBB + base + lane * 16, ldsB + base);
  }
  __syncthreads();

  int wm = wave & 1, wn = wave >> 1;
  int m0 = wm * 64, n0 = wn * 32;
  f4 zero = {0.f, 0.f, 0.f, 0.f};
  f4 acc[4][2];
#pragma unroll
  for (int i = 0; i < 4; ++i) { acc[i][0] = zero; acc[i][1] = zero; }

  for (int st = 0; st < 18; ++st) {
    int cur = st & 1;
    if (st < 17) {
      int base = wave << 10;
      gl_lds16((const char*)wBB + (long)(st + 1) * 4096 + base + lane * 16,
               ldsB + ((cur ^ 1) << 12) + base);
    }
    int tap = st >> 1, s = st & 1;
    int kx = tap % 3, rowk = tap / 3;
    const char* arow = lds + rowk * AROWB;
    int cbb = s * 64 + kc * 16;
    bh8 af[4], bfr[2];
#pragma unroll
    for (int mf = 0; mf < 4; ++mf) {
      int pxl = kx + m0 + mf * 16 + i16;
      af[mf] = *(const bh8*)(arow + pxl * 128 + (cbb ^ ((pxl & 7) << 4)));
    }
    const char* bbuf = ldsB + (cur << 12);
#pragma unroll
    for (int nf = 0; nf < 2; ++nf) {
      int oc = n0 + nf * 16 + i16;
      bfr[nf] = *(const bh8*)(bbuf + oc * 64 + ((kc * 16) ^ ((oc & 3) << 4)));
    }
#pragma unroll
    for (int mf = 0; mf < 4; ++mf)
#pragma unroll
      for (int nf = 0; nf < 2; ++nf)
        acc[mf][nf] = __builtin_amdgcn_mfma_f32_16x16x32_bf16(af[mf], bfr[nf], acc[mf][nf], 0, 0, 0);
    __syncthreads();
  }

#pragma unroll
  for (int nf = 0; nf < 2; ++nf) {
    float s1 = 0.f, s2 = 0.f;
#pragma unroll
    for (int mf = 0; mf < 4; ++mf)
#pragma unroll
      for (int r = 0; r < 4; ++r) {
        float v = acc[mf][nf][r];
        s1 += v; s2 += v * v;
      }
    s1 += __shfl_xor(s1, 16); s2 += __shfl_xor(s2, 16);
    s1 += __shfl_xor(s1, 32); s2 += __shfl_xor(s2, 32);
    if (lane < 16) {
      int oc = n0 + nf * 16 + i16;
      atomicAdd(&statf[oc * 2], s1);
      atomicAdd(&statf[oc * 2 + 1], s2);
    }
  }
  __syncthreads();
#pragma unroll
  for (int nf = 0; nf < 2; ++nf) {
    int oc2 = (n0 + nf * 16 + i16) * 2;
#pragma unroll
    for (int mf = 0; mf < 4; ++mf)
#pragma unroll
      for (int r = 0; r < 4; ++r) {
        int px = m0 + mf * 16 + kc * 4 + r;
        *(unsigned short*)(lds + px * 128 + (oc2 ^ ((px & 7) << 4))) = f2b(acc[mf][nf][r]);
      }
  }
  __syncthreads();
  unsigned short* y2b = y2 + (long)b * NP * 64;
#pragma unroll
  for (int it = 0; it < 4; ++it) {
    int slot = (it * 256 + tid) * 16;
    int px = slot >> 7, cb = slot & 127;
    int cbs = cb ^ ((px & 7) << 4);
    f4 v = *(const f4*)(lds + px * 128 + cbs);
    *(f4*)((char*)(y2b + (long)(y * 256 + x0 + px) * 64) + cb) = v;
  }
  if (tid < 128) statp[(long)bid * 128 + tid] = statf[tid];
}

// ---------------- K7a/K7b: BN stat reduce (conv B) ----------------
__global__ __launch_bounds__(128) void k7a(const float* __restrict__ statp, float* __restrict__ p2) {
  int rblk = blockIdx.x, tid = threadIdx.x;
  float s = 0;
  for (int k = 0; k < 8; ++k) s += statp[(long)(rblk * 8 + k) * 128 + tid];
  p2[rblk * 128 + tid] = s;
}

__global__ __launch_bounds__(128) void k7b(const float* __restrict__ p2,
                                           const float* __restrict__ g2,
                                           const float* __restrict__ be2,
                                           float* __restrict__ bnB) {
  int tid = threadIdx.x;
  float s = 0;
  for (int k = 0; k < 128; ++k) s += p2[k * 128 + tid];
  __shared__ float sm[128];
  sm[tid] = s;
  __syncthreads();
  if (tid < 64) {
    int oc = tid;
    float mean = sm[oc * 2] * (1.f / 131072.f);
    float var = sm[oc * 2 + 1] * (1.f / 131072.f) - mean * mean;
    float sc = g2[oc] * rsqrtf(fmaxf(var, 0.f) + 1e-5f);
    bnB[oc * 2] = sc;
    bnB[oc * 2 + 1] = be2[oc] - mean * sc;
  }
}

// ---------------- K8: out = relu(relu(bnA(y_init)) + bnB(y2)), NCHW f32 ----------------
__global__ __launch_bounds__(256) void k8_final(const unsigned short* __restrict__ yws,
                                                const unsigned short* __restrict__ y2,
                                                const float* __restrict__ bnA,
                                                const float* __restrict__ bnB,
                                                float* __restrict__ out) {
  __shared__ float tr[64 * 77];
  int tid = threadIdx.x;
  int blk = blockIdx.x;
  int b = blk >> 10, rem = blk & 1023;
  int y = rem >> 2, xq0 = rem & 3;
  int x0 = xq0 * 64;
  int px = tid >> 2, cg = (tid & 3) * 16;
  long prow = (long)b * NP + y * 256 + x0 + px;
  const unsigned short* ysrc = yws + prow * 128 + cg;
  const unsigned short* y2src = y2 + prow * 64 + cg;
  bh8 va = *(const bh8*)ysrc;
  bh8 vb = *(const bh8*)(ysrc + 8);
  bh8 wa = *(const bh8*)y2src;
  bh8 wb = *(const bh8*)(y2src + 8);
#pragma unroll
  for (int j = 0; j < 16; ++j) {
    int c = cg + j;
    unsigned short uy = (unsigned short)(j < 8 ? va[j] : vb[j - 8]);
    unsigned short u2 = (unsigned short)(j < 8 ? wa[j] : wb[j - 8]);
    float iv = fmaxf(b2f(uy) * bnA[c * 2] + bnA[c * 2 + 1], 0.f);
    float cv = b2f(u2) * bnB[c * 2] + bnB[c * 2 + 1];
    tr[c * 77 + px] = fmaxf(iv + cv, 0.f);
  }
  __syncthreads();
  int c = tid >> 2, xq = tid & 3;
  float* orow = out + ((long)(b * 64 + c)) * NP + y * 256 + x0 + xq * 16;
  const float* trow = &tr[c * 77 + xq * 16];
#pragma unroll
  for (int j = 0; j < 16; j += 4) {
    float4 v = make_float4(trow[j], trow[j + 1], trow[j + 2], trow[j + 3]);
    *(float4*)(orow + j) = v;
  }
}

extern "C" void kernel_launch(void* const* d_in, const int* in_sizes, int n_in,
                              void* d_out, int out_size, void* d_ws, size_t ws_size,
                              hipStream_t stream) {
  if (ws_size < (size_t)WS_NEED) return;
  const float* x_i  = (const float*)d_in[0];
  const float* x_e  = (const float*)d_in[1];
  const float* y    = (const float*)d_in[2];
  const float* temp = (const float*)d_in[3];
  const float* wq   = (const float*)d_in[4];
  const float* bq   = (const float*)d_in[5];
  const float* wk   = (const float*)d_in[6];
  const float* bk   = (const float*)d_in[7];
  const float* wv   = (const float*)d_in[8];
  const float* wo   = (const float*)d_in[10];
  const float* w_init = (const float*)d_in[12];
  const float* g_init = (const float*)d_in[14];
  const float* be_init= (const float*)d_in[15];
  const float* w1   = (const float*)d_in[16];
  const float* g1   = (const float*)d_in[18];
  const float* be1  = (const float*)d_in[19];
  const float* w2   = (const float*)d_in[20];
  const float* g2   = (const float*)d_in[22];
  const float* be2  = (const float*)d_in[23];

  char* ws = (char*)d_ws;
  float* gp    = (float*)(ws + WSO_GP);
  float* Mw    = (float*)(ws + WSO_M);
  float* Sw    = (float*)(ws + WSO_S);
  float* Pw    = (float*)(ws + WSO_P);
  float* QKw   = (float*)(ws + WSO_QK);
  float* Gw    = (float*)(ws + WSO_G);
  float* wkT   = (float*)(ws + WSO_WKT);
  unsigned short* wBA = (unsigned short*)(ws + WSO_WBA);
  unsigned short* wBB = (unsigned short*)(ws + WSO_WBB);
  unsigned short* fused = (unsigned short*)(ws + WSO_FUSED);
  unsigned short* yws   = (unsigned short*)(ws + WSO_Y);
  float* statA = (float*)(ws + WSO_STATA);
  float* p2A   = (float*)(ws + WSO_P2A);
  float* bnA   = (float*)(ws + WSO_BNA);
  unsigned short* y2w = (unsigned short*)(ws + WSO_Y2);
  float* statB = (float*)(ws + WSO_STATB);
  float* p2B   = (float*)(ws + WSO_P2B);
  float* bnB   = (float*)(ws + WSO_BNB);
  float* out   = (float*)d_out;

  hipLaunchKernelGGL(k0_prep, dim3(1024), dim3(256), 0, stream,
                     w_init, w1, w2, wk, wBA, wBB, wkT);
  hipLaunchKernelGGL(k1_gram, dim3(128, 2), dim3(256), 0, stream, x_i, x_e, y, gp);
  hipLaunchKernelGGL(k1_reduce, dim3(162), dim3(256), 0, stream, gp, Mw, Sw);
  hipLaunchKernelGGL(k2a, dim3(5, 2), dim3(256), 0, stream, wq, wk, Mw, Pw);
  hipLaunchKernelGGL(k2b, dim3(2, 2), dim3(256), 0, stream, Pw, wkT, QKw);
  hipLaunchKernelGGL(k2c, dim3(2), dim3(256), 0, stream,
                     Pw, QKw, Sw, wq, wk, wv, wo, bq, bk, temp, Gw);
  hipLaunchKernelGGL(k3_fused, dim3(1024, 2), dim3(512), 0, stream, x_i, x_e, Gw, fused);
  hipLaunchKernelGGL(k4_mfma, dim3(1024), dim3(256), 0, stream, fused, wBA, yws, statA);
  hipLaunchKernelGGL(k5a, dim3(128), dim3(256), 0, stream, statA, p2A);
  hipLaunchKernelGGL(k5b, dim3(1), dim3(256), 0, stream, p2A, g_init, be_init, g1, be1, bnA);
  hipLaunchKernelGGL(k6_mfma, dim3(1024), dim3(256), 0, stream, yws, wBB, bnA, y2w, statB);
  hipLaunchKernelGGL(k7a, dim3(128), dim3(128), 0, stream, statB, p2B);
  hipLaunchKernelGGL(k7b, dim3(1), dim3(128), 0, stream, p2B, g2, be2, bnB);
  hipLaunchKernelGGL(k8_final, dim3(2048), dim3(256), 0, stream, yws, y2w, bnA, bnB, out);
}

// Round 3
// 333.579 us; speedup vs baseline: 6.9527x; 1.2552x over previous
//
#include <hip/hip_runtime.h>
#include <hip/hip_bf16.h>

#define DI __device__ __forceinline__

typedef __attribute__((ext_vector_type(8))) short bh8;
typedef __attribute__((ext_vector_type(4))) float f4;

constexpr int  NP        = 65536;              // H*W per batch
constexpr long GP_STRIDE = 20672;              // 5*4096 + 192

// workspace byte offsets
constexpr long WSO_GP    = 0;                                  // [2][128][GP_STRIDE] f32
constexpr long WSO_M     = WSO_GP    + 2L*128*GP_STRIDE*4;     // [2][5][4096] f32
constexpr long WSO_S     = WSO_M     + 2L*5*4096*4;            // [2][192] f32
constexpr long WSO_P     = WSO_S     + 2L*192*4;               // [2][5][4096] f32
constexpr long WSO_QK    = WSO_P     + 2L*5*4096*4;            // [2][2][4096] f32
constexpr long WSO_G     = WSO_QK    + 2L*2*4096*4;            // [2][2][4096] f32
constexpr long WSO_WKT   = WSO_G     + 2L*2*4096*4;            // [4096] f32
constexpr long WSO_WBA   = WSO_WKT   + 4096L*4;                // [54][128][32] bf16 (swizzled)
constexpr long WSO_WBB   = WSO_WBA   + 221184L*2;              // [18][64][32] bf16 (swizzled)
constexpr long WSO_FUSED = WSO_WBB   + 36864L*2;               // [2][NP][192] bf16 pixel-major
constexpr long WSO_Y     = WSO_FUSED + 2L*NP*192*2;            // [2][NP][128] bf16 pixel-major
constexpr long WSO_STATA = WSO_Y     + 2L*NP*128*2;            // [1024][256] f32
constexpr long WSO_P2A   = WSO_STATA + 1024L*256*4;            // [128][256] f32
constexpr long WSO_BNA   = WSO_P2A   + 128L*256*4;             // [256] f32
constexpr long WSO_Y2    = WSO_BNA   + 256L*4;                 // [2][NP][64] bf16 pixel-major
constexpr long WSO_STATB = WSO_Y2    + 2L*NP*64*2;             // [1024][128] f32
constexpr long WSO_P2B   = WSO_STATB + 1024L*128*4;            // [128][128] f32
constexpr long WSO_BNB   = WSO_P2B   + 128L*128*4;             // [128] f32
constexpr long WS_NEED   = WSO_BNB   + 128L*4;

constexpr int AROWB = 136 * 128;   // bytes per row-strip in conv LDS (136 px * 128 B)
constexpr int ALDSB = 3 * AROWB;   // 52224

DI float b2f(unsigned short u) { return __uint_as_float(((unsigned)u) << 16); }
DI unsigned short f2b(float f) {
  __hip_bfloat16 h = __float2bfloat16(f);
  return *(unsigned short*)&h;
}
DI void gl_lds16(const void* g, void* l) {
  __builtin_amdgcn_global_load_lds(
      (const __attribute__((address_space(1))) unsigned int*)g,
      (__attribute__((address_space(3))) unsigned int*)l, 16, 0, 0);
}

// ---------------- K0: weight re-layouts (bf16, B^T, bank-swizzled) ----------------
__global__ __launch_bounds__(256) void k0_prep(const float* __restrict__ w_init,
                                               const float* __restrict__ w1,
                                               const float* __restrict__ w2,
                                               const float* __restrict__ wk,
                                               unsigned short* __restrict__ wBA,
                                               unsigned short* __restrict__ wBB,
                                               float* __restrict__ wkT) {
  int i = blockIdx.x * 256 + threadIdx.x;
  if (i < 221184) {                 // conv A weights: step = chunk*18 + tap*2 + s
    int step = i >> 12;
    int rem = i & 4095;
    int oc = rem >> 5, kk = rem & 31;
    int chunk = step / 18, r2 = step % 18;
    int tap = r2 >> 1, s = r2 & 1;
    int c = chunk * 64 + s * 32 + kk;
    float v = (oc < 64) ? w_init[(oc * 192 + c) * 9 + tap]
                        : w1[((oc - 64) * 192 + c) * 9 + tap];
    wBA[(step << 12) + (oc << 5) + (kk ^ ((oc & 3) << 3))] = f2b(v);
  } else if (i < 258048) {          // conv B weights: step = tap*2 + s
    int j = i - 221184;
    int step = j >> 11;
    int rem = j & 2047;
    int oc = rem >> 5, kk = rem & 31;
    int tap = step >> 1, s = step & 1;
    int c = s * 32 + kk;
    wBB[(step << 11) + (oc << 5) + (kk ^ ((oc & 3) << 3))] = f2b(w2[(oc * 64 + c) * 9 + tap]);
  } else {
    int j = i - 258048;
    int kkk = j >> 6, oo = j & 63;
    wkT[j] = wk[oo * 64 + kkk];
  }
}

// ---------------- K1: per-b Gram matrices via MFMA (hi/lo bf16 split) ----------------
__global__ __launch_bounds__(512, 2) void k1_gram(const float* __restrict__ xi,
                                                  const float* __restrict__ xe,
                                                  const float* __restrict__ yy,
                                                  float* __restrict__ gp) {
  __shared__ alignas(16) char lds[2 * 49152];   // dbuf x [3t][2p][64c][128B] swizzled
  int tid = threadIdx.x;
  int lane = tid & 63, wave = tid >> 6;
  int i_t = wave & 3, jh = wave >> 2;
  int blk = blockIdx.x, b = blockIdx.y;
  const float* srcs[3];
  srcs[0] = yy + (long)b * 64 * NP;
  srcs[1] = xe + (long)b * 64 * NP;
  srcs[2] = xi + (long)b * 64 * NP;

  f4 zero = {0.f, 0.f, 0.f, 0.f};
  f4 acc[5][2];
#pragma unroll
  for (int g = 0; g < 5; ++g) { acc[g][0] = zero; acc[g][1] = zero; }
  float rs[6] = {0.f, 0.f, 0.f, 0.f, 0.f, 0.f};

  int rowv[6], col4v[6], tv[6], cv[6];
#pragma unroll
  for (int ii = 0; ii < 6; ++ii) {
    int li = ii * 512 + tid;
    rowv[ii] = li >> 4; col4v[ii] = li & 15;
    tv[ii] = rowv[ii] >> 6; cv[ii] = rowv[ii] & 63;
  }

  float4 v[6];
#define LOADS(S)                                                                \
  { int n0 = blk * 512 + (S) * 64;                                              \
    _Pragma("unroll") for (int ii = 0; ii < 6; ++ii)                            \
      v[ii] = *(const float4*)(srcs[tv[ii]] + (long)cv[ii] * NP + n0 + col4v[ii] * 4); }
#define CVTW(BUF)                                                               \
  { _Pragma("unroll") for (int ii = 0; ii < 6; ++ii) {                          \
      rs[ii] += v[ii].x + v[ii].y + v[ii].z + v[ii].w;                          \
      ushort4 hi, lo;                                                           \
      hi.x = f2b(v[ii].x); lo.x = f2b(v[ii].x - b2f(hi.x));                     \
      hi.y = f2b(v[ii].y); lo.y = f2b(v[ii].y - b2f(hi.y));                     \
      hi.z = f2b(v[ii].z); lo.z = f2b(v[ii].z - b2f(hi.z));                     \
      hi.w = f2b(v[ii].w); lo.w = f2b(v[ii].w - b2f(hi.w));                     \
      int base = (BUF) * 49152 + (tv[ii] * 2 * 64 + cv[ii]) * 128;              \
      int colo = (col4v[ii] * 8) ^ ((cv[ii] & 7) << 4);                         \
      *(ushort4*)(lds + base + colo) = hi;                                      \
      *(ushort4*)(lds + base + 8192 + colo) = lo; } }

  LOADS(0)
  CVTW(0)
  for (int s = 0; s < 8; ++s) {
    int buf = s & 1;
    __syncthreads();
    if (s < 7) LOADS(s + 1)     // issued post-barrier: hide under ds_read+MFMA
    const char* lb = lds + buf * 49152;
#pragma unroll
    for (int kk = 0; kk < 2; ++kk) {
      bh8 ah[3], al[3];
#pragma unroll
      for (int t = 0; t < 3; ++t) {
        int cc = i_t * 16 + (lane & 15);
        int col = (kk * 64 + ((lane >> 4) << 4)) ^ ((cc & 7) << 4);
        ah[t] = *(const bh8*)(lb + ((t * 2) * 64 + cc) * 128 + col);
        al[t] = *(const bh8*)(lb + ((t * 2) * 64 + cc) * 128 + 8192 + col);
      }
#pragma unroll
      for (int jj = 0; jj < 2; ++jj) {
        int j = jh * 2 + jj;
        bh8 bh_[3], bl_[3];
#pragma unroll
        for (int t = 0; t < 3; ++t) {
          int dd = j * 16 + (lane & 15);
          int col = (kk * 64 + ((lane >> 4) << 4)) ^ ((dd & 7) << 4);
          bh_[t] = *(const bh8*)(lb + ((t * 2) * 64 + dd) * 128 + col);
          bl_[t] = *(const bh8*)(lb + ((t * 2) * 64 + dd) * 128 + 8192 + col);
        }
#define GRAM(G, TA, TB)                                                            \
        acc[G][jj] = __builtin_amdgcn_mfma_f32_16x16x32_bf16(ah[TA], bh_[TB], acc[G][jj], 0, 0, 0); \
        acc[G][jj] = __builtin_amdgcn_mfma_f32_16x16x32_bf16(ah[TA], bl_[TB], acc[G][jj], 0, 0, 0); \
        acc[G][jj] = __builtin_amdgcn_mfma_f32_16x16x32_bf16(al[TA], bh_[TB], acc[G][jj], 0, 0, 0);
        GRAM(0, 0, 1) GRAM(1, 0, 2) GRAM(2, 0, 0) GRAM(3, 1, 1) GRAM(4, 2, 2)
#undef GRAM
      }
    }
    if (s < 7) CVTW(buf ^ 1)
  }
#undef LOADS
#undef CVTW

  float* outp = gp + ((long)b * 128 + blk) * GP_STRIDE;
#pragma unroll
  for (int g = 0; g < 5; ++g)
#pragma unroll
    for (int jj = 0; jj < 2; ++jj) {
      int j = jh * 2 + jj;
#pragma unroll
      for (int r = 0; r < 4; ++r) {
        int cg = i_t * 16 + ((lane >> 4) << 2) + r;
        int dg = j * 16 + (lane & 15);
        outp[g * 4096 + cg * 64 + dg] = acc[g][jj][r];
      }
    }
#pragma unroll
  for (int ii = 0; ii < 6; ++ii) {
    float s = rs[ii];
    s += __shfl_xor(s, 1); s += __shfl_xor(s, 2);
    s += __shfl_xor(s, 4); s += __shfl_xor(s, 8);
    if ((lane & 15) == 0) outp[5 * 4096 + rowv[ii]] = s;
  }
}

// ---------------- K1r: reduce Gram partials ----------------
__global__ __launch_bounds__(256) void k1_reduce(const float* __restrict__ gp,
                                                 float* __restrict__ M,
                                                 float* __restrict__ S) {
  int i = blockIdx.x * 256 + threadIdx.x;
  if (i >= 2 * GP_STRIDE) return;
  int b = i / GP_STRIDE, o = i % GP_STRIDE;
  const float* p = gp + (long)b * 128 * GP_STRIDE + o;
  float s = 0;
  for (int k = 0; k < 128; ++k) s += p[(long)k * GP_STRIDE];
  if (o < 20480) M[b * 20480 + o] = s;
  else           S[b * 192 + (o - 20480)] = s;
}

// ---------------- K2a: P_g = W * M_g ----------------
__global__ __launch_bounds__(256) void k2a(const float* __restrict__ wq,
                                           const float* __restrict__ wk,
                                           const float* __restrict__ M,
                                           float* __restrict__ P) {
  int b = blockIdx.y, g = blockIdx.x;
  const float* W = (g < 3) ? wq : wk;
  const float* Mg = M + b * 20480 + g * 4096;
  float* Pg = P + b * 20480 + g * 4096;
  int tid = threadIdx.x;
  int i = tid >> 2, jg = (tid & 3) * 16;
  float acc[16] = {0};
  for (int k = 0; k < 64; ++k) {
    float w = W[i * 64 + k];
    const float* mrow = Mg + k * 64 + jg;
#pragma unroll
    for (int j = 0; j < 16; ++j) acc[j] = fmaf(w, mrow[j], acc[j]);
  }
#pragma unroll
  for (int j = 0; j < 16; ++j) Pg[i * 64 + jg + j] = acc[j];
}

// ---------------- K2b: QK = P{0,1} * Wk^T ----------------
__global__ __launch_bounds__(256) void k2b(const float* __restrict__ P,
                                           const float* __restrict__ wkT,
                                           float* __restrict__ QK) {
  int b = blockIdx.y, v = blockIdx.x;
  const float* Pg = P + b * 20480 + v * 4096;
  float* out = QK + (b * 2 + v) * 4096;
  int tid = threadIdx.x;
  int i = tid >> 2, jg = (tid & 3) * 16;
  float acc[16] = {0};
  for (int k = 0; k < 64; ++k) {
    float w = Pg[i * 64 + k];
    const float* mrow = wkT + k * 64 + jg;
#pragma unroll
    for (int j = 0; j < 16; ++j) acc[j] = fmaf(w, mrow[j], acc[j]);
  }
#pragma unroll
  for (int j = 0; j < 16; ++j) out[i * 64 + jg + j] = acc[j];
}

// ---------------- K2c: norms, softmax, Gv = wo*BD(attn)*Wv ----------------
__global__ __launch_bounds__(256) void k2c(const float* __restrict__ P,
                                           const float* __restrict__ QK,
                                           const float* __restrict__ Ssum,
                                           const float* __restrict__ wq,
                                           const float* __restrict__ wk,
                                           const float* __restrict__ wv,
                                           const float* __restrict__ wo,
                                           const float* __restrict__ bq,
                                           const float* __restrict__ bk,
                                           const float* __restrict__ temp,
                                           float* __restrict__ G) {
  int b = blockIdx.x, tid = threadIdx.x;
  __shared__ float u[64], vxe[64], vxi[64], nq[64], nke[64], nki[64];
  __shared__ float attn[64][8];
  __shared__ float Gm[64][64];
  if (tid < 64) {
    int i = tid;
    float uu = 0, ve = 0, vi = 0, dq = 0, dke = 0, dki = 0;
    const float* p2 = P + b * 20480 + 2 * 4096 + i * 64;
    const float* p3 = P + b * 20480 + 3 * 4096 + i * 64;
    const float* p4 = P + b * 20480 + 4 * 4096 + i * 64;
    const float* sy = Ssum + b * 192;
    const float* sxe = sy + 64;
    const float* sxi = sy + 128;
#pragma unroll 8
    for (int k = 0; k < 64; ++k) {
      float wqk = wq[i * 64 + k], wkk = wk[i * 64 + k];
      uu += wqk * sy[k];  ve += wkk * sxe[k];  vi += wkk * sxi[k];
      dq += p2[k] * wqk;  dke += p3[k] * wkk;  dki += p4[k] * wkk;
    }
    u[i] = uu; vxe[i] = ve; vxi[i] = vi;
    const float N = 65536.f;
    float bqi = bq[i], bki = bk[i];
    nq[i]  = fmaxf(sqrtf(fmaxf(dq  + 2.f * uu * bqi + N * bqi * bqi, 0.f)), 1e-12f);
    nke[i] = fmaxf(sqrtf(fmaxf(dke + 2.f * ve * bki + N * bki * bki, 0.f)), 1e-12f);
    nki[i] = fmaxf(sqrtf(fmaxf(dki + 2.f * vi * bki + N * bki * bki, 0.f)), 1e-12f);
  }
  __syncthreads();
  int o = tid >> 2, jg = (tid & 3) * 16;
  for (int variant = 0; variant < 2; ++variant) {
    if (tid < 64) {
      int i = tid, h = i >> 3;
      const float* qrow = QK + (b * 2 + variant) * 4096 + i * 64;
      const float* nk = variant ? nki : nke;
      const float* vx = variant ? vxi : vxe;
      float t = temp[h];
      float bqi = bq[i];
      float lg[8];
      float mx = -1e30f;
#pragma unroll
      for (int d = 0; d < 8; ++d) {
        int j = h * 8 + d;
        float val = qrow[j] + u[i] * bk[j] + bqi * vx[j] + 65536.f * bqi * bk[j];
        val = val / (nq[i] * nk[j]) * t;
        lg[d] = val;
        mx = fmaxf(mx, val);
      }
      float se = 0;
#pragma unroll
      for (int d = 0; d < 8; ++d) { lg[d] = expf(lg[d] - mx); se += lg[d]; }
      float inv = 1.f / se;
#pragma unroll
      for (int d = 0; d < 8; ++d) attn[i][d] = lg[d] * inv;
    }
    __syncthreads();
#pragma unroll
    for (int jj = 0; jj < 16; ++jj) {
      int j = jg + jj, h = j >> 3, d = j & 7;
      float s = 0;
#pragma unroll
      for (int c = 0; c < 8; ++c) s += wo[o * 64 + h * 8 + c] * attn[h * 8 + c][d];
      Gm[o][j] = s;
    }
    __syncthreads();
    float acc[16] = {0};
    for (int m = 0; m < 64; ++m) {
      float gm = Gm[o][m];
      const float* wr = wv + m * 64 + jg;
#pragma unroll
      for (int jj = 0; jj < 16; ++jj) acc[jj] = fmaf(gm, wr[jj], acc[jj]);
    }
    float* go = G + ((long)(b * 2 + variant)) * 4096 + o * 64 + jg;
#pragma unroll
    for (int jj = 0; jj < 16; ++jj) go[jj] = acc[jj];
    __syncthreads();
  }
}

// ---------------- K3: fused = [Gv_e*x_i ; Gv_e*x_e ; Gv_i*x_i], pixel-major bf16 ----------------
__global__ __launch_bounds__(512) void k3_fused(const float* __restrict__ xi_g,
                                                const float* __restrict__ xe_g,
                                                const float* __restrict__ G,
                                                unsigned short* __restrict__ fused) {
  __shared__ float xt[2 * 64 * 66];                // [t][px][66]
  __shared__ float Gf[128 * 66];                   // [v*64+oc][66]
  __shared__ alignas(16) unsigned short ot[64 * 200];  // [px][200] (192 used)
  int tid = threadIdx.x;
  int b = blockIdx.y;
  int px0 = blockIdx.x * 64;

  for (int it = 0; it < 16; ++it) {
    int slot = it * 512 + tid;          // 8192 = 2*64*64
    int t = slot >> 12, rem = slot & 4095;
    int c = rem >> 6, px = rem & 63;
    const float* src = (t ? xe_g : xi_g) + ((long)b * 64 + c) * NP + px0 + px;
    xt[(t * 64 + px) * 66 + c] = *src;
  }
  const float* Gb = G + (long)b * 2 * 4096;
  for (int it = 0; it < 16; ++it) {
    int slot = it * 512 + tid;          // 8192
    Gf[(slot >> 6) * 66 + (slot & 63)] = Gb[slot];
  }
  __syncthreads();

  int g = tid >> 6, px = tid & 63;      // wave = oc-group (G reads broadcast)
  float a0[8] = {0.f}, a1[8] = {0.f}, a2[8] = {0.f};
  const float* xv = &xt[(0 * 64 + px) * 66];
  const float* xw = &xt[(1 * 64 + px) * 66];
  for (int c2 = 0; c2 < 32; ++c2) {
    float vix = xv[c2 * 2], viy = xv[c2 * 2 + 1];
    float vex = xw[c2 * 2], vey = xw[c2 * 2 + 1];
#pragma unroll
    for (int j = 0; j < 8; ++j) {
      int oc = g * 8 + j;
      float gex = Gf[oc * 66 + c2 * 2], gey = Gf[oc * 66 + c2 * 2 + 1];
      float gix = Gf[(64 + oc) * 66 + c2 * 2], giy = Gf[(64 + oc) * 66 + c2 * 2 + 1];
      a0[j] += gex * vix + gey * viy;
      a1[j] += gex * vex + gey * vey;
      a2[j] += gix * vix + giy * viy;
    }
  }
  bh8 p0, p1, p2;
#pragma unroll
  for (int j = 0; j < 8; ++j) {
    p0[j] = (short)f2b(a0[j]);
    p1[j] = (short)f2b(a1[j]);
    p2[j] = (short)f2b(a2[j]);
  }
  *(bh8*)&ot[px * 200 + g * 8]       = p0;
  *(bh8*)&ot[px * 200 + 64 + g * 8]  = p1;
  *(bh8*)&ot[px * 200 + 128 + g * 8] = p2;
  __syncthreads();

  unsigned short* fb = fused + ((long)b * NP + px0) * 192;
  for (int it = 0; it < 3; ++it) {
    int idx = it * 512 + tid;           // 1536 chunks of 16B
    int p = idx / 24, cc = idx % 24;
    f4 v = *(const f4*)&ot[p * 200 + cc * 8];
    *(f4*)((char*)(fb + (long)p * 192) + cc * 16) = v;
  }
}

// ---------------- K4: conv3x3 reflect 192->128 via MFMA + BN stat partials ----------------
__global__ __launch_bounds__(256, 2) void k4_mfma(const unsigned short* __restrict__ fused,
                                                  const unsigned short* __restrict__ wBA,
                                                  unsigned short* __restrict__ yout,
                                                  float* __restrict__ statp) {
  __shared__ alignas(16) char lds[ALDSB + 16384 + 1024];
  char* ldsB = lds + ALDSB;
  float* statf = (float*)(lds + ALDSB + 16384);

  int tid = threadIdx.x;
  int wave = tid >> 6, lane = tid & 63;
  int kc = lane >> 4, i16 = lane & 15;

  int bid = blockIdx.x;
  int blk = (bid & 7) * 128 + (bid >> 3);   // bijective XCD swizzle (1024 % 8 == 0)
  int b = blk >> 9, y = (blk >> 1) & 255, xt = blk & 1;
  int x0 = xt << 7;
  int rows[3] = {y > 0 ? y - 1 : 1, y, y < 255 ? y + 1 : 254};

  const unsigned short* fb = fused + (long)b * NP * 192;
  statf[tid] = 0.f;

  int wm = wave & 1, wn = wave >> 1;
  int m0 = wm * 64, n0 = wn * 64;

  f4 zero = {0.f, 0.f, 0.f, 0.f};
  f4 acc[4][4];
#pragma unroll
  for (int i = 0; i < 4; ++i)
#pragma unroll
    for (int j = 0; j < 4; ++j) acc[i][j] = zero;

  for (int ch = 0; ch < 3; ++ch) {
    __syncthreads();                        // protect A region reuse
    long ch0b = (long)ch * 128;             // byte offset within 384-B fused row
#pragma unroll
    for (int it = 0; it < 13; ++it) {
      int base = (wave * 13 + it) << 10;
      if (base < ALDSB) {
        int slot = base + lane * 16;
        int row = slot / AROWB;
        int rr = slot - row * AROWB;
        int px = rr >> 7, cb = rr & 127;
        int pxl = px < 130 ? px : 129;
        int gx = x0 - 1 + pxl;
        gx = gx < 0 ? 1 : (gx > 255 ? 254 : gx);
        int cbs = cb ^ ((px & 7) << 4);
        const char* src = (const char*)(fb + (long)(rows[row] * 256 + gx) * 192) + ch0b + cbs;
        gl_lds16(src, lds + base);
      }
    }
    {
      const char* wsrc = (const char*)wBA + (long)(ch * 18) * 8192;
#pragma unroll
      for (int it = 0; it < 2; ++it) {
        int base = (wave * 2 + it) << 10;
        gl_lds16(wsrc + base + lane * 16, ldsB + base);
      }
    }
    __syncthreads();

    for (int st = 0; st < 18; ++st) {
      int cur = st & 1;
      if (st < 17) {
        const char* wsrc = (const char*)wBA + (long)(ch * 18 + st + 1) * 8192;
#pragma unroll
        for (int it = 0; it < 2; ++it) {
          int base = (wave * 2 + it) << 10;
          gl_lds16(wsrc + base + lane * 16, ldsB + ((cur ^ 1) << 13) + base);
        }
      }
      int tap = st >> 1, s = st & 1;
      int kx = tap % 3, rowk = tap / 3;
      const char* arow = lds + rowk * AROWB;
      int cbb = s * 64 + kc * 16;
      bh8 af[4], bfr[4];
#pragma unroll
      for (int mf = 0; mf < 4; ++mf) {
        int pxl = kx + m0 + mf * 16 + i16;
        af[mf] = *(const bh8*)(arow + pxl * 128 + (cbb ^ ((pxl & 7) << 4)));
      }
      const char* bbuf = ldsB + (cur << 13);
#pragma unroll
      for (int nf = 0; nf < 4; ++nf) {
        int oc = n0 + nf * 16 + i16;
        bfr[nf] = *(const bh8*)(bbuf + oc * 64 + ((kc * 16) ^ ((oc & 3) << 4)));
      }
#pragma unroll
      for (int mf = 0; mf < 4; ++mf)
#pragma unroll
        for (int nf = 0; nf < 4; ++nf)
          acc[mf][nf] = __builtin_amdgcn_mfma_f32_16x16x32_bf16(af[mf], bfr[nf], acc[mf][nf], 0, 0, 0);
      __syncthreads();
    }
  }

#pragma unroll
  for (int nf = 0; nf < 4; ++nf) {
    float s1 = 0.f, s2 = 0.f;
#pragma unroll
    for (int mf = 0; mf < 4; ++mf)
#pragma unroll
      for (int r = 0; r < 4; ++r) {
        float v = acc[mf][nf][r];
        s1 += v; s2 += v * v;
      }
    s1 += __shfl_xor(s1, 16); s2 += __shfl_xor(s2, 16);
    s1 += __shfl_xor(s1, 32); s2 += __shfl_xor(s2, 32);
    if (lane < 16) {
      int oc = n0 + nf * 16 + i16;
      atomicAdd(&statf[oc * 2], s1);
      atomicAdd(&statf[oc * 2 + 1], s2);
    }
  }
  __syncthreads();
#pragma unroll
  for (int nf = 0; nf < 4; ++nf) {
    int oc2 = (n0 + nf * 16 + i16) * 2;
#pragma unroll
    for (int mf = 0; mf < 4; ++mf)
#pragma unroll
      for (int r = 0; r < 4; ++r) {
        int px = m0 + mf * 16 + kc * 4 + r;
        *(unsigned short*)(lds + px * 256 + (oc2 ^ ((px & 7) << 4))) = f2b(acc[mf][nf][r]);
      }
  }
  __syncthreads();
  unsigned short* yb = yout + (long)b * NP * 128;
#pragma unroll
  for (int it = 0; it < 8; ++it) {
    int slot = (it * 256 + tid) * 16;
    int px = slot >> 8, cb = slot & 255;
    int cbs = cb ^ ((px & 7) << 4);
    f4 v = *(const f4*)(lds + px * 256 + cbs);
    *(f4*)((char*)(yb + (long)(y * 256 + x0 + px) * 128) + cb) = v;
  }
  statp[(long)bid * 256 + tid] = statf[tid];
}

// ---------------- K5a/K5b: BN stat reduce (conv A) ----------------
__global__ __launch_bounds__(256) void k5a(const float* __restrict__ statp, float* __restrict__ p2) {
  int rblk = blockIdx.x, tid = threadIdx.x;
  float s = 0;
  for (int k = 0; k < 8; ++k) s += statp[(long)(rblk * 8 + k) * 256 + tid];
  p2[rblk * 256 + tid] = s;
}

__global__ __launch_bounds__(256) void k5b(const float* __restrict__ p2,
                                           const float* __restrict__ g_init,
                                           const float* __restrict__ be_init,
                                           const float* __restrict__ g1,
                                           const float* __restrict__ be1,
                                           float* __restrict__ bnA) {
  int tid = threadIdx.x;
  float s = 0;
  for (int k = 0; k < 128; ++k) s += p2[k * 256 + tid];
  __shared__ float sm[256];
  sm[tid] = s;
  __syncthreads();
  if (tid < 128) {
    int oc = tid;
    float mean = sm[oc * 2] * (1.f / 131072.f);
    float var = sm[oc * 2 + 1] * (1.f / 131072.f) - mean * mean;
    float g  = oc < 64 ? g_init[oc] : g1[oc - 64];
    float be = oc < 64 ? be_init[oc] : be1[oc - 64];
    float sc = g * rsqrtf(fmaxf(var, 0.f) + 1e-5f);
    bnA[oc * 2] = sc;
    bnA[oc * 2 + 1] = be - mean * sc;
  }
}

// ---------------- K6: conv3x3 reflect relu(bn1(y1)) -> 64 via MFMA + stats ----------------
__global__ __launch_bounds__(256, 2) void k6_mfma(const unsigned short* __restrict__ yws,
                                                  const unsigned short* __restrict__ wBB,
                                                  const float* __restrict__ bnA,
                                                  unsigned short* __restrict__ y2,
                                                  float* __restrict__ statp) {
  __shared__ alignas(16) char lds[ALDSB + 8192 + 512];
  char* ldsB = lds + ALDSB;
  float* statf = (float*)(lds + ALDSB + 8192);

  int tid = threadIdx.x;
  int wave = tid >> 6, lane = tid & 63;
  int kc = lane >> 4, i16 = lane & 15;

  int bid = blockIdx.x;
  int blk = (bid & 7) * 128 + (bid >> 3);
  int b = blk >> 9, y = (blk >> 1) & 255, xt = blk & 1;
  int x0 = xt << 7;
  int rows[3] = {y > 0 ? y - 1 : 1, y, y < 255 ? y + 1 : 254};

  if (tid < 128) statf[tid] = 0.f;

  int c0 = (tid & 7) * 8;
  float sc[8], bi[8];
#pragma unroll
  for (int e = 0; e < 8; ++e) {
    int cc = 64 + c0 + e;
    sc[e] = bnA[cc * 2];
    bi[e] = bnA[cc * 2 + 1];
  }
  const unsigned short* yb = yws + (long)b * NP * 128;
  int pbase = tid >> 3;
  for (int r = 0; r < 13; ++r) {
    int p = pbase + r * 32;
    if (p < 408) {
      int row = p / 136, pxs = p - row * 136;
      int pxl = pxs < 130 ? pxs : 129;
      int gx = x0 - 1 + pxl;
      gx = gx < 0 ? 1 : (gx > 255 ? 254 : gx);
      const unsigned short* src = yb + (long)(rows[row] * 256 + gx) * 128 + 64 + c0;
      bh8 v = *(const bh8*)src;
      bh8 o;
#pragma unroll
      for (int e = 0; e < 8; ++e) {
        float f = fmaxf(b2f((unsigned short)v[e]) * sc[e] + bi[e], 0.f);
        o[e] = (short)f2b(f);
      }
      *(bh8*)(lds + p * 128 + ((c0 * 2) ^ ((pxs & 7) << 4))) = o;
    }
  }
  {
    int base = wave << 10;
    gl_lds16((const char*)wBB + base + lane * 16, ldsB + base);
  }
  __syncthreads();

  int wm = wave & 1, wn = wave >> 1;
  int m0 = wm * 64, n0 = wn * 32;
  f4 zero = {0.f, 0.f, 0.f, 0.f};
  f4 acc[4][2];
#pragma unroll
  for (int i = 0; i < 4; ++i) { acc[i][0] = zero; acc[i][1] = zero; }

  for (int st = 0; st < 18; ++st) {
    int cur = st & 1;
    if (st < 17) {
      int base = wave << 10;
      gl_lds16((const char*)wBB + (long)(st + 1) * 4096 + base + lane * 16,
               ldsB + ((cur ^ 1) << 12) + base);
    }
    int tap = st >> 1, s = st & 1;
    int kx = tap % 3, rowk = tap / 3;
    const char* arow = lds + rowk * AROWB;
    int cbb = s * 64 + kc * 16;
    bh8 af[4], bfr[2];
#pragma unroll
    for (int mf = 0; mf < 4; ++mf) {
      int pxl = kx + m0 + mf * 16 + i16;
      af[mf] = *(const bh8*)(arow + pxl * 128 + (cbb ^ ((pxl & 7) << 4)));
    }
    const char* bbuf = ldsB + (cur << 12);
#pragma unroll
    for (int nf = 0; nf < 2; ++nf) {
      int oc = n0 + nf * 16 + i16;
      bfr[nf] = *(const bh8*)(bbuf + oc * 64 + ((kc * 16) ^ ((oc & 3) << 4)));
    }
#pragma unroll
    for (int mf = 0; mf < 4; ++mf)
#pragma unroll
      for (int nf = 0; nf < 2; ++nf)
        acc[mf][nf] = __builtin_amdgcn_mfma_f32_16x16x32_bf16(af[mf], bfr[nf], acc[mf][nf], 0, 0, 0);
    __syncthreads();
  }

#pragma unroll
  for (int nf = 0; nf < 2; ++nf) {
    float s1 = 0.f, s2 = 0.f;
#pragma unroll
    for (int mf = 0; mf < 4; ++mf)
#pragma unroll
      for (int r = 0; r < 4; ++r) {
        float v = acc[mf][nf][r];
        s1 += v; s2 += v * v;
      }
    s1 += __shfl_xor(s1, 16); s2 += __shfl_xor(s2, 16);
    s1 += __shfl_xor(s1, 32); s2 += __shfl_xor(s2, 32);
    if (lane < 16) {
      int oc = n0 + nf * 16 + i16;
      atomicAdd(&statf[oc * 2], s1);
      atomicAdd(&statf[oc * 2 + 1], s2);
    }
  }
  __syncthreads();
#pragma unroll
  for (int nf = 0; nf < 2; ++nf) {
    int oc2 = (n0 + nf * 16 + i16) * 2;
#pragma unroll
    for (int mf = 0; mf < 4; ++mf)
#pragma unroll
      for (int r = 0; r < 4; ++r) {
        int px = m0 + mf * 16 + kc * 4 + r;
        *(unsigned short*)(lds + px * 128 + (oc2 ^ ((px & 7) << 4))) = f2b(acc[mf][nf][r]);
      }
  }
  __syncthreads();
  unsigned short* y2b = y2 + (long)b * NP * 64;
#pragma unroll
  for (int it = 0; it < 4; ++it) {
    int slot = (it * 256 + tid) * 16;
    int px = slot >> 7, cb = slot & 127;
    int cbs = cb ^ ((px & 7) << 4);
    f4 v = *(const f4*)(lds + px * 128 + cbs);
    *(f4*)((char*)(y2b + (long)(y * 256 + x0 + px) * 64) + cb) = v;
  }
  if (tid < 128) statp[(long)bid * 128 + tid] = statf[tid];
}

// ---------------- K7a/K7b: BN stat reduce (conv B) ----------------
__global__ __launch_bounds__(128) void k7a(const float* __restrict__ statp, float* __restrict__ p2) {
  int rblk = blockIdx.x, tid = threadIdx.x;
  float s = 0;
  for (int k = 0; k < 8; ++k) s += statp[(long)(rblk * 8 + k) * 128 + tid];
  p2[rblk * 128 + tid] = s;
}

__global__ __launch_bounds__(128) void k7b(const float* __restrict__ p2,
                                           const float* __restrict__ g2,
                                           const float* __restrict__ be2,
                                           float* __restrict__ bnB) {
  int tid = threadIdx.x;
  float s = 0;
  for (int k = 0; k < 128; ++k) s += p2[k * 128 + tid];
  __shared__ float sm[128];
  sm[tid] = s;
  __syncthreads();
  if (tid < 64) {
    int oc = tid;
    float mean = sm[oc * 2] * (1.f / 131072.f);
    float var = sm[oc * 2 + 1] * (1.f / 131072.f) - mean * mean;
    float sc = g2[oc] * rsqrtf(fmaxf(var, 0.f) + 1e-5f);
    bnB[oc * 2] = sc;
    bnB[oc * 2 + 1] = be2[oc] - mean * sc;
  }
}

// ---------------- K8: out = relu(relu(bnA(y_init)) + bnB(y2)), NCHW f32 ----------------
__global__ __launch_bounds__(256) void k8_final(const unsigned short* __restrict__ yws,
                                                const unsigned short* __restrict__ y2,
                                                const float* __restrict__ bnA,
                                                const float* __restrict__ bnB,
                                                float* __restrict__ out) {
  __shared__ float tr[64 * 77];
  int tid = threadIdx.x;
  int blk = blockIdx.x;
  int b = blk >> 10, rem = blk & 1023;
  int y = rem >> 2, xq0 = rem & 3;
  int x0 = xq0 * 64;
  int px = tid >> 2, cg = (tid & 3) * 16;
  long prow = (long)b * NP + y * 256 + x0 + px;
  const unsigned short* ysrc = yws + prow * 128 + cg;
  const unsigned short* y2src = y2 + prow * 64 + cg;
  bh8 va = *(const bh8*)ysrc;
  bh8 vb = *(const bh8*)(ysrc + 8);
  bh8 wa = *(const bh8*)y2src;
  bh8 wb = *(const bh8*)(y2src + 8);
#pragma unroll
  for (int j = 0; j < 16; ++j) {
    int c = cg + j;
    unsigned short uy = (unsigned short)(j < 8 ? va[j] : vb[j - 8]);
    unsigned short u2 = (unsigned short)(j < 8 ? wa[j] : wb[j - 8]);
    float iv = fmaxf(b2f(uy) * bnA[c * 2] + bnA[c * 2 + 1], 0.f);
    float cv = b2f(u2) * bnB[c * 2] + bnB[c * 2 + 1];
    tr[c * 77 + px] = fmaxf(iv + cv, 0.f);
  }
  __syncthreads();
  int c = tid >> 2, xq = tid & 3;
  float* orow = out + ((long)(b * 64 + c)) * NP + y * 256 + x0 + xq * 16;
  const float* trow = &tr[c * 77 + xq * 16];
#pragma unroll
  for (int j = 0; j < 16; j += 4) {
    float4 v = make_float4(trow[j], trow[j + 1], trow[j + 2], trow[j + 3]);
    *(float4*)(orow + j) = v;
  }
}

extern "C" void kernel_launch(void* const* d_in, const int* in_sizes, int n_in,
                              void* d_out, int out_size, void* d_ws, size_t ws_size,
                              hipStream_t stream) {
  if (ws_size < (size_t)WS_NEED) return;
  const float* x_i  = (const float*)d_in[0];
  const float* x_e  = (const float*)d_in[1];
  const float* y    = (const float*)d_in[2];
  const float* temp = (const float*)d_in[3];
  const float* wq   = (const float*)d_in[4];
  const float* bq   = (const float*)d_in[5];
  const float* wk   = (const float*)d_in[6];
  const float* bk   = (const float*)d_in[7];
  const float* wv   = (const float*)d_in[8];
  const float* wo   = (const float*)d_in[10];
  const float* w_init = (const float*)d_in[12];
  const float* g_init = (const float*)d_in[14];
  const float* be_init= (const float*)d_in[15];
  const float* w1   = (const float*)d_in[16];
  const float* g1   = (const float*)d_in[18];
  const float* be1  = (const float*)d_in[19];
  const float* w2   = (const float*)d_in[20];
  const float* g2   = (const float*)d_in[22];
  const float* be2  = (const float*)d_in[23];

  char* ws = (char*)d_ws;
  float* gp    = (float*)(ws + WSO_GP);
  float* Mw    = (float*)(ws + WSO_M);
  float* Sw    = (float*)(ws + WSO_S);
  float* Pw    = (float*)(ws + WSO_P);
  float* QKw   = (float*)(ws + WSO_QK);
  float* Gw    = (float*)(ws + WSO_G);
  float* wkT   = (float*)(ws + WSO_WKT);
  unsigned short* wBA = (unsigned short*)(ws + WSO_WBA);
  unsigned short* wBB = (unsigned short*)(ws + WSO_WBB);
  unsigned short* fused = (unsigned short*)(ws + WSO_FUSED);
  unsigned short* yws   = (unsigned short*)(ws + WSO_Y);
  float* statA = (float*)(ws + WSO_STATA);
  float* p2A   = (float*)(ws + WSO_P2A);
  float* bnA   = (float*)(ws + WSO_BNA);
  unsigned short* y2w = (unsigned short*)(ws + WSO_Y2);
  float* statB = (float*)(ws + WSO_STATB);
  float* p2B   = (float*)(ws + WSO_P2B);
  float* bnB   = (float*)(ws + WSO_BNB);
  float* out   = (float*)d_out;

  hipLaunchKernelGGL(k0_prep, dim3(1024), dim3(256), 0, stream,
                     w_init, w1, w2, wk, wBA, wBB, wkT);
  hipLaunchKernelGGL(k1_gram, dim3(128, 2), dim3(512), 0, stream, x_i, x_e, y, gp);
  hipLaunchKernelGGL(k1_reduce, dim3(162), dim3(256), 0, stream, gp, Mw, Sw);
  hipLaunchKernelGGL(k2a, dim3(5, 2), dim3(256), 0, stream, wq, wk, Mw, Pw);
  hipLaunchKernelGGL(k2b, dim3(2, 2), dim3(256), 0, stream, Pw, wkT, QKw);
  hipLaunchKernelGGL(k2c, dim3(2), dim3(256), 0, stream,
                     Pw, QKw, Sw, wq, wk, wv, wo, bq, bk, temp, Gw);
  hipLaunchKernelGGL(k3_fused, dim3(1024, 2), dim3(512), 0, stream, x_i, x_e, Gw, fused);
  hipLaunchKernelGGL(k4_mfma, dim3(1024), dim3(256), 0, stream, fused, wBA, yws, statA);
  hipLaunchKernelGGL(k5a, dim3(128), dim3(256), 0, stream, statA, p2A);
  hipLaunchKernelGGL(k5b, dim3(1), dim3(256), 0, stream, p2A, g_init, be_init, g1, be1, bnA);
  hipLaunchKernelGGL(k6_mfma, dim3(1024), dim3(256), 0, stream, yws, wBB, bnA, y2w, statB);
  hipLaunchKernelGGL(k7a, dim3(128), dim3(128), 0, stream, statB, p2B);
  hipLaunchKernelGGL(k7b, dim3(1), dim3(128), 0, stream, p2B, g2, be2, bnB);
  hipLaunchKernelGGL(k8_final, dim3(2048), dim3(256), 0, stream, yws, y2w, bnA, bnB, out);
}